// Round 1
// baseline (2558.132 us; speedup 1.0000x reference)
//
#include <hip/hip_runtime.h>

// Problem constants
// a: (256,128,128)  b: (4,256,64,400)  E=256 NH=8 DH=32  B=400 Lq=128 Lk=64
#define HA 128
#define WA 128
#define PIX 16384          // 128*128
#define C1 256
#define H1 128
#define H2 64
#define W2 400
#define MS 51200           // H1*W2 samples
#define MB 25600           // H2*W2

// ===================== coords: x,y, scatter idx, counts =====================
__global__ __launch_bounds__(256) void coords_kernel(
    const float* __restrict__ rots, const float* __restrict__ fxs,
    const float* __restrict__ cxs, int j,
    float* __restrict__ xarr, float* __restrict__ yarr,
    int* __restrict__ idxarr, float* __restrict__ cnt)
{
  int s = blockIdx.x * 256 + threadIdx.x;      // 0..51199, s = h*400 + w
  int h = s / 400;
  int w = s - h * 400;
  float fx = fxs[j], cx = cxs[j];
  const float* R = rots + j * 9;
  float cr = R[3];        // rots[1][0]
  float sr = -R[0];       // -rots[0][0]
  float t = (2.0f * (float)w + 1.0f - cx) / fx;      // tan(ang)
  float inv = 1.0f / sqrtf(1.0f + t * t);            // cos(ang)
  float ca = (cr + sr * t) * inv;                    // cr*cos + sr*sin
  float sa = (cr * t - sr) * inv;                    // -sr*cos + cr*sin
  float rad = ((float)h * (1.0f / 127.0f)) * 90.50966799187808f;
  float x = 64.0f + rad * ca;
  float y = 64.0f - rad * sa;
  xarr[s] = x;
  yarr[s] = y;
  int xi = (int)fminf(fmaxf(rintf(x), 0.0f), 127.0f);
  int yi = (int)fminf(fmaxf(rintf(y), 0.0f), 127.0f);
  int pix = yi * 128 + xi;
  idxarr[s] = pix;
  atomicAdd(&cnt[pix], 1.0f);
}

// ===================== bilinear sampler: a_rect[c][h][w] =====================
__global__ __launch_bounds__(256) void sample_kernel(
    const float* __restrict__ a_cur, const float* __restrict__ xarr,
    const float* __restrict__ yarr, float* __restrict__ a_rect)
{
  int s = blockIdx.x * 256 + threadIdx.x;   // sample index
  int c = blockIdx.y;                       // channel
  float x = fminf(fmaxf(xarr[s], 0.0f), 127.0f);
  float y = fminf(fmaxf(yarr[s], 0.0f), 127.0f);
  float x0f = floorf(x), y0f = floorf(y);
  int x0 = (int)x0f, y0 = (int)y0f;
  int x1 = min(x0 + 1, 127), y1 = min(y0 + 1, 127);
  float wx = x - x0f, wy = y - y0f;
  const float* img = a_cur + (size_t)c * PIX;
  float v00 = img[y0 * 128 + x0];
  float v01 = img[y0 * 128 + x1];
  float v10 = img[y1 * 128 + x0];
  float v11 = img[y1 * 128 + x1];
  float val = v00 * (1.0f - wx) * (1.0f - wy) + v01 * wx * (1.0f - wy)
            + v10 * (1.0f - wx) * wy + v11 * wx * wy;
  a_rect[(size_t)c * MS + s] = val;
}

// ===================== GEMM (A K-major): C = A^T * W^T + rowbias ==========
// A[k][m] (stride Astride), W[f][k] (256-k rows), out[(w*Hdim+h)*256+f] += bias[h*256+f]
// m = h*400 + w
__global__ __launch_bounds__(256) void gemmT_kernel(
    const float* __restrict__ A, int Astride,
    const float* __restrict__ Wt, const float* __restrict__ bias,
    float* __restrict__ Cout, int Hdim)
{
  __shared__ float As[16][64];
  __shared__ float Ws[16][65];
  int m0 = blockIdx.x * 64;
  int n0 = blockIdx.y * 64;
  int tid = threadIdx.x;
  int tx = tid & 15, ty = tid >> 4;
  float acc[4][4] = {};
  for (int k0 = 0; k0 < 256; k0 += 16) {
    {
      int r = tid >> 4;            // k row 0..15
      int cq = (tid & 15) << 2;    // m col
      float4 v = *(const float4*)(A + (size_t)(k0 + r) * Astride + m0 + cq);
      *(float4*)(&As[r][cq]) = v;
    }
    {
      int f = tid >> 2;            // 0..63
      int kq = (tid & 3) << 2;
      float4 v = *(const float4*)(Wt + (size_t)(n0 + f) * 256 + k0 + kq);
      Ws[kq + 0][f] = v.x; Ws[kq + 1][f] = v.y;
      Ws[kq + 2][f] = v.z; Ws[kq + 3][f] = v.w;
    }
    __syncthreads();
#pragma unroll
    for (int kk = 0; kk < 16; ++kk) {
      float a[4], b[4];
#pragma unroll
      for (int i = 0; i < 4; ++i) a[i] = As[kk][ty * 4 + i];
#pragma unroll
      for (int jj = 0; jj < 4; ++jj) b[jj] = Ws[kk][tx * 4 + jj];
#pragma unroll
      for (int i = 0; i < 4; ++i)
#pragma unroll
        for (int jj = 0; jj < 4; ++jj) acc[i][jj] += a[i] * b[jj];
    }
    __syncthreads();
  }
#pragma unroll
  for (int i = 0; i < 4; ++i) {
    int m = m0 + ty * 4 + i;
    int h = m / 400;
    int w = m - h * 400;
    size_t obase = (size_t)(w * Hdim + h) * 256;
    int f = n0 + tx * 4;
    float4 bv = *(const float4*)(bias + h * 256 + f);
    float4 ov;
    ov.x = acc[i][0] + bv.x; ov.y = acc[i][1] + bv.y;
    ov.z = acc[i][2] + bv.z; ov.w = acc[i][3] + bv.w;
    *(float4*)(Cout + obase + f) = ov;
  }
}

// ===================== GEMM (A M-major): C = A * W^T =====================
// mode 0: Cout[m*256+f] = acc + biasf[f]
// mode 1: scatter: m=(w*128+h); s=h*400+w; atomicAdd(rest[f*16384+idx[s]], acc+biasf[f])
__global__ __launch_bounds__(256) void gemmN_kernel(
    const float* __restrict__ A, const float* __restrict__ Wt,
    const float* __restrict__ biasf, float* __restrict__ Cout,
    int mode, const int* __restrict__ idxarr, float* __restrict__ rest)
{
  __shared__ float As[64][17];
  __shared__ float Ws[16][65];
  int m0 = blockIdx.x * 64;
  int n0 = blockIdx.y * 64;
  int tid = threadIdx.x;
  int tx = tid & 15, ty = tid >> 4;
  float acc[4][4] = {};
  for (int k0 = 0; k0 < 256; k0 += 16) {
    {
      int m = tid >> 2;            // 0..63
      int kq = (tid & 3) << 2;
      float4 v = *(const float4*)(A + (size_t)(m0 + m) * 256 + k0 + kq);
      As[m][kq + 0] = v.x; As[m][kq + 1] = v.y;
      As[m][kq + 2] = v.z; As[m][kq + 3] = v.w;
    }
    {
      int f = tid >> 2;
      int kq = (tid & 3) << 2;
      float4 v = *(const float4*)(Wt + (size_t)(n0 + f) * 256 + k0 + kq);
      Ws[kq + 0][f] = v.x; Ws[kq + 1][f] = v.y;
      Ws[kq + 2][f] = v.z; Ws[kq + 3][f] = v.w;
    }
    __syncthreads();
#pragma unroll
    for (int kk = 0; kk < 16; ++kk) {
      float a[4], b[4];
#pragma unroll
      for (int i = 0; i < 4; ++i) a[i] = As[ty * 4 + i][kk];
#pragma unroll
      for (int jj = 0; jj < 4; ++jj) b[jj] = Ws[kk][tx * 4 + jj];
#pragma unroll
      for (int i = 0; i < 4; ++i)
#pragma unroll
        for (int jj = 0; jj < 4; ++jj) acc[i][jj] += a[i] * b[jj];
    }
    __syncthreads();
  }
  if (mode == 0) {
#pragma unroll
    for (int i = 0; i < 4; ++i) {
      int m = m0 + ty * 4 + i;
      int f = n0 + tx * 4;
      float4 bv = *(const float4*)(biasf + f);
      float4 ov;
      ov.x = acc[i][0] + bv.x; ov.y = acc[i][1] + bv.y;
      ov.z = acc[i][2] + bv.z; ov.w = acc[i][3] + bv.w;
      *(float4*)(Cout + (size_t)m * 256 + f) = ov;
    }
  } else {
#pragma unroll
    for (int i = 0; i < 4; ++i) {
      int m = m0 + ty * 4 + i;
      int w = m >> 7;              // m = w*128 + h
      int h = m & 127;
      int s = h * 400 + w;
      int pix = idxarr[s];
#pragma unroll
      for (int jj = 0; jj < 4; ++jj) {
        int f = n0 + tx * 4 + jj;
        atomicAdd(rest + (size_t)f * PIX + pix, acc[i][jj] + biasf[f]);
      }
    }
  }
}

// ===================== GEMM A[m][k] * B[k][n] (effective weights) ==========
__global__ __launch_bounds__(256) void gemm_ab_kernel(
    const float* __restrict__ in_w, const float* __restrict__ Wq,
    const float* __restrict__ Wk, const float* __restrict__ Wv,
    float* __restrict__ weff)
{
  int z = blockIdx.z;
  const float* A = in_w + (size_t)z * 65536;
  const float* B = (z == 0) ? Wq : ((z == 1) ? Wk : Wv);
  float* C = weff + (size_t)z * 65536;
  __shared__ float As[64][17];
  __shared__ float Bs[16][64];
  int m0 = blockIdx.x * 64;
  int n0 = blockIdx.y * 64;
  int tid = threadIdx.x;
  int tx = tid & 15, ty = tid >> 4;
  float acc[4][4] = {};
  for (int k0 = 0; k0 < 256; k0 += 16) {
    {
      int m = tid >> 2;
      int kq = (tid & 3) << 2;
      float4 v = *(const float4*)(A + (size_t)(m0 + m) * 256 + k0 + kq);
      As[m][kq + 0] = v.x; As[m][kq + 1] = v.y;
      As[m][kq + 2] = v.z; As[m][kq + 3] = v.w;
    }
    {
      int k = tid >> 4;
      int nq = (tid & 15) << 2;
      float4 v = *(const float4*)(B + (size_t)(k0 + k) * 256 + n0 + nq);
      *(float4*)(&Bs[k][nq]) = v;
    }
    __syncthreads();
#pragma unroll
    for (int kk = 0; kk < 16; ++kk) {
      float a[4], b[4];
#pragma unroll
      for (int i = 0; i < 4; ++i) a[i] = As[ty * 4 + i][kk];
#pragma unroll
      for (int jj = 0; jj < 4; ++jj) b[jj] = Bs[kk][tx * 4 + jj];
#pragma unroll
      for (int i = 0; i < 4; ++i)
#pragma unroll
        for (int jj = 0; jj < 4; ++jj) acc[i][jj] += a[i] * b[jj];
    }
    __syncthreads();
  }
#pragma unroll
  for (int i = 0; i < 4; ++i) {
    int m = m0 + ty * 4 + i;
    *(float4*)(C + (size_t)m * 256 + n0 + tx * 4) = *(float4*)&acc[i][0];
  }
}

// ===================== effective biases =====================
__global__ void beff_kernel(const float* __restrict__ in_w, const float* __restrict__ in_b,
                            const float* __restrict__ bq, const float* __restrict__ bk,
                            const float* __restrict__ bv, float* __restrict__ beff)
{
  int z = blockIdx.x;
  int f = threadIdx.x;
  const float* bsrc = (z == 0) ? bq : ((z == 1) ? bk : bv);
  const float* row = in_w + (size_t)(z * 256 + f) * 256;
  float acc = in_b[z * 256 + f];
  for (int e = 0; e < 256; ++e) acc += row[e] * bsrc[e];
  beff[z * 256 + f] = acc;
}

// ===================== attention =====================
// per-block: one (b,head); 128 threads = one query row each
__global__ __launch_bounds__(128) void attn_kernel(
    const float* __restrict__ qq, const float* __restrict__ kk,
    const float* __restrict__ vv, float* __restrict__ obuf)
{
  int b = blockIdx.x >> 3;
  int hd = blockIdx.x & 7;
  __shared__ float ks[64][32];
  __shared__ float vs[64][32];
  int t = threadIdx.x;
#pragma unroll
  for (int i = 0; i < 16; ++i) {
    int e = i * 128 + t;
    int ki = e >> 5, d = e & 31;
    ks[ki][d] = kk[(size_t)(b * 64 + ki) * 256 + hd * 32 + d];
    vs[ki][d] = vv[(size_t)(b * 64 + ki) * 256 + hd * 32 + d];
  }
  __syncthreads();
  float qr[32];
  const float* qp = qq + (size_t)(b * 128 + t) * 256 + hd * 32;
#pragma unroll
  for (int d = 0; d < 32; d += 4) {
    float4 v = *(const float4*)(qp + d);
    qr[d] = v.x; qr[d + 1] = v.y; qr[d + 2] = v.z; qr[d + 3] = v.w;
  }
  float s[64];
  float mx = -1e30f;
  const float scale = 0.17677669529663687f;   // 1/sqrt(32)
#pragma unroll
  for (int ki = 0; ki < 64; ++ki) {
    const float4* kr = (const float4*)(&ks[ki][0]);
    float acc = 0.0f;
#pragma unroll
    for (int q4 = 0; q4 < 8; ++q4) {
      float4 kv = kr[q4];
      acc += qr[q4 * 4 + 0] * kv.x + qr[q4 * 4 + 1] * kv.y
           + qr[q4 * 4 + 2] * kv.z + qr[q4 * 4 + 3] * kv.w;
    }
    acc *= scale;
    s[ki] = acc;
    mx = fmaxf(mx, acc);
  }
  float l = 0.0f;
#pragma unroll
  for (int ki = 0; ki < 64; ++ki) { s[ki] = __expf(s[ki] - mx); l += s[ki]; }
  float invl = 1.0f / l;
  float o[32];
#pragma unroll
  for (int d = 0; d < 32; ++d) o[d] = 0.0f;
#pragma unroll
  for (int ki = 0; ki < 64; ++ki) {
    float p = s[ki];
    const float4* vr = (const float4*)(&vs[ki][0]);
#pragma unroll
    for (int d4 = 0; d4 < 8; ++d4) {
      float4 v4 = vr[d4];
      o[d4 * 4 + 0] += p * v4.x; o[d4 * 4 + 1] += p * v4.y;
      o[d4 * 4 + 2] += p * v4.z; o[d4 * 4 + 3] += p * v4.w;
    }
  }
  float* op = obuf + (size_t)(b * 128 + t) * 256 + hd * 32;
#pragma unroll
  for (int d = 0; d < 32; d += 4) {
    float4 v;
    v.x = o[d] * invl; v.y = o[d + 1] * invl;
    v.z = o[d + 2] * invl; v.w = o[d + 3] * invl;
    *(float4*)(op + d) = v;
  }
}

// ===================== residual update / final =====================
__global__ __launch_bounds__(256) void update_kernel(
    float* __restrict__ a_cur, const float* __restrict__ rest, const float* __restrict__ cnt)
{
  size_t t = (size_t)blockIdx.x * 256 + threadIdx.x;
  int p = (int)(t & (PIX - 1));
  float c = cnt[p];
  c = (c == 0.0f) ? 1.0f : c;
  a_cur[t] += rest[t] / c;
}

__global__ __launch_bounds__(256) void final_kernel(
    float* __restrict__ out, const float* __restrict__ a_cur,
    const float* __restrict__ rest, const float* __restrict__ cnt)
{
  size_t t = (size_t)blockIdx.x * 256 + threadIdx.x;
  int p = (int)(t & (PIX - 1));
  float c = cnt[p];
  c = (c == 0.0f) ? 1.0f : c;
  out[t] = a_cur[t] + 2.0f * rest[t] / c;
}

// ===================== launch =====================
extern "C" void kernel_launch(void* const* d_in, const int* in_sizes, int n_in,
                              void* d_out, int out_size, void* d_ws, size_t ws_size,
                              hipStream_t stream) {
  const float* list_a = (const float*)d_in[0];
  const float* list_b = (const float*)d_in[1];
  const float* rots   = (const float*)d_in[3];
  const float* fxs    = (const float*)d_in[5];
  const float* cxs    = (const float*)d_in[6];
  const float* pos_a  = (const float*)d_in[7];
  const float* pos_b  = (const float*)d_in[8];
  const float* Wq     = (const float*)d_in[9];
  const float* bq     = (const float*)d_in[10];
  const float* Wk     = (const float*)d_in[11];
  const float* bk     = (const float*)d_in[12];
  const float* Wv     = (const float*)d_in[13];
  const float* bv     = (const float*)d_in[14];
  const float* in_w   = (const float*)d_in[15];
  const float* in_b   = (const float*)d_in[16];
  const float* out_w  = (const float*)d_in[17];
  const float* out_b  = (const float*)d_in[18];

  float* ws    = (float*)d_ws;
  float* weff  = ws;                      // 3*65536
  float* beff  = weff + 196608;           // 768
  float* qpos  = beff + 768;              // 32768
  float* kpos  = qpos + 32768;            // 16384
  float* vpos  = kpos + 16384;            // 16384
  float* a_cur = vpos + 16384;            // 4194304
  float* xarr  = a_cur + 4194304;         // 51200
  float* yarr  = xarr + 51200;            // 51200
  int*   idxarr = (int*)(yarr + 51200);   // 51200
  float* rest  = yarr + 102400;           // 4194304  (contiguous with cnt for one memset)
  float* cnt   = rest + 4194304;          // 16384
  float* a_rect = cnt + 16384;            // 13107200 (doubles as o_buf)
  float* qq    = a_rect + 13107200;       // 13107200
  float* kkb   = qq + 13107200;           // 6553600
  float* vvb   = kkb + 6553600;           // 6553600

  hipMemcpyAsync(a_cur, list_a, (size_t)4194304 * sizeof(float),
                 hipMemcpyDeviceToDevice, stream);

  // effective weights + biases (tiny)
  gemm_ab_kernel<<<dim3(4, 4, 3), 256, 0, stream>>>(in_w, Wq, Wk, Wv, weff);
  beff_kernel<<<3, 256, 0, stream>>>(in_w, in_b, bq, bk, bv, beff);

  // positional bias tables: pos @ Weff^T + beff
  gemmN_kernel<<<dim3(2, 4), 256, 0, stream>>>(pos_a, weff, beff, qpos, 0, nullptr, nullptr);
  gemmN_kernel<<<dim3(1, 4), 256, 0, stream>>>(pos_b, weff + 65536, beff + 256, kpos, 0, nullptr, nullptr);
  gemmN_kernel<<<dim3(1, 4), 256, 0, stream>>>(pos_b, weff + 131072, beff + 512, vpos, 0, nullptr, nullptr);

  for (int jj = 0; jj < 2; ++jj) {
    int j = jj ? 3 : 0;
    hipMemsetAsync(rest, 0, (size_t)(4194304 + 16384) * sizeof(float), stream);
    coords_kernel<<<200, 256, 0, stream>>>(rots, fxs, cxs, j, xarr, yarr, idxarr, cnt);
    sample_kernel<<<dim3(200, 256), 256, 0, stream>>>(a_cur, xarr, yarr, a_rect);
    // qq = (a_rect + pos) @ Wq_eff^T : A K-major
    gemmT_kernel<<<dim3(800, 4), 256, 0, stream>>>(a_rect, MS, weff, qpos, qq, 128);
    const float* bsrc = list_b + (size_t)j * 6553600;
    gemmT_kernel<<<dim3(400, 4), 256, 0, stream>>>(bsrc, MB, weff + 65536, kpos, kkb, 64);
    gemmT_kernel<<<dim3(400, 4), 256, 0, stream>>>(bsrc, MB, weff + 131072, vpos, vvb, 64);
    attn_kernel<<<3200, 128, 0, stream>>>(qq, kkb, vvb, a_rect);   // o into a_rect
    // out-proj + scatter-add
    gemmN_kernel<<<dim3(800, 4), 256, 0, stream>>>(a_rect, out_w, out_b, nullptr, 1, idxarr, rest);
    if (jj == 0) {
      update_kernel<<<16384, 256, 0, stream>>>(a_cur, rest, cnt);
    } else {
      final_kernel<<<16384, 256, 0, stream>>>((float*)d_out, a_cur, rest, cnt);
    }
  }
}

// Round 2
// 1497.668 us; speedup vs baseline: 1.7081x; 1.7081x over previous
//
#include <hip/hip_runtime.h>

// Problem constants
// a: (256,128,128)  b: (4,256,64,400)  E=256 NH=8 DH=32  B=400 Lq=128 Lk=64
#define HA 128
#define WA 128
#define PIX 16384          // 128*128
#define C1 256
#define H1 128
#define H2 64
#define W2 400
#define MS 51200           // H1*W2 samples
#define MB 25600           // H2*W2

// ===================== coords: x,y, scatter idx, counts =====================
__global__ __launch_bounds__(256) void coords_kernel(
    const float* __restrict__ rots, const float* __restrict__ fxs,
    const float* __restrict__ cxs, int j,
    float* __restrict__ xarr, float* __restrict__ yarr,
    int* __restrict__ idxarr, float* __restrict__ cnt)
{
  int s = blockIdx.x * 256 + threadIdx.x;      // 0..51199, s = h*400 + w
  int h = s / 400;
  int w = s - h * 400;
  float fx = fxs[j], cx = cxs[j];
  const float* R = rots + j * 9;
  float cr = R[3];        // rots[1][0]
  float sr = -R[0];       // -rots[0][0]
  float t = (2.0f * (float)w + 1.0f - cx) / fx;      // tan(ang)
  float inv = 1.0f / sqrtf(1.0f + t * t);            // cos(ang)
  float ca = (cr + sr * t) * inv;                    // cr*cos + sr*sin
  float sa = (cr * t - sr) * inv;                    // -sr*cos + cr*sin
  float rad = ((float)h * (1.0f / 127.0f)) * 90.50966799187808f;
  float x = 64.0f + rad * ca;
  float y = 64.0f - rad * sa;
  xarr[s] = x;
  yarr[s] = y;
  int xi = (int)fminf(fmaxf(rintf(x), 0.0f), 127.0f);
  int yi = (int)fminf(fmaxf(rintf(y), 0.0f), 127.0f);
  int pix = yi * 128 + xi;
  idxarr[s] = pix;
  atomicAdd(&cnt[pix], 1.0f);
}

// ===================== prefix scan over pixel counts =====================
__global__ __launch_bounds__(256) void prefix_kernel(
    const float* __restrict__ cnt, int* __restrict__ offsets)
{
  __shared__ int sh[256];
  int t = threadIdx.x;
  int base = t * 64;
  int sum = 0;
  for (int i = 0; i < 64; ++i) sum += (int)cnt[base + i];
  sh[t] = sum;
  __syncthreads();
  for (int d = 1; d < 256; d <<= 1) {
    int v = (t >= d) ? sh[t - d] : 0;
    __syncthreads();
    sh[t] += v;
    __syncthreads();
  }
  int run = sh[t] - sum;   // exclusive prefix for this thread's chunk
  for (int i = 0; i < 64; ++i) {
    offsets[base + i] = run;
    run += (int)cnt[base + i];
  }
}

// ===================== fill sorted sample lists =====================
__global__ __launch_bounds__(256) void fill_kernel(
    const int* __restrict__ idxarr, const int* __restrict__ offsets,
    int* __restrict__ cursor, int* __restrict__ order)
{
  int s = blockIdx.x * 256 + threadIdx.x;
  int pix = idxarr[s];
  int pos = offsets[pix] + atomicAdd(&cursor[pix], 1);
  // store the attention-output row index m = w*128 + h  (s = h*400 + w)
  order[pos] = (s % 400) * 128 + (s / 400);
}

// ===================== bilinear sampler: a_rect[c][h][w] =====================
__global__ __launch_bounds__(256) void sample_kernel(
    const float* __restrict__ a_cur, const float* __restrict__ xarr,
    const float* __restrict__ yarr, float* __restrict__ a_rect)
{
  int s = blockIdx.x * 256 + threadIdx.x;   // sample index
  int c = blockIdx.y;                       // channel
  float x = fminf(fmaxf(xarr[s], 0.0f), 127.0f);
  float y = fminf(fmaxf(yarr[s], 0.0f), 127.0f);
  float x0f = floorf(x), y0f = floorf(y);
  int x0 = (int)x0f, y0 = (int)y0f;
  int x1 = min(x0 + 1, 127), y1 = min(y0 + 1, 127);
  float wx = x - x0f, wy = y - y0f;
  const float* img = a_cur + (size_t)c * PIX;
  float v00 = img[y0 * 128 + x0];
  float v01 = img[y0 * 128 + x1];
  float v10 = img[y1 * 128 + x0];
  float v11 = img[y1 * 128 + x1];
  float val = v00 * (1.0f - wx) * (1.0f - wy) + v01 * wx * (1.0f - wy)
            + v10 * (1.0f - wx) * wy + v11 * wx * wy;
  a_rect[(size_t)c * MS + s] = val;
}

// ===================== GEMM (A K-major): C = A^T * W^T + rowbias ==========
// A[k][m] (stride Astride), W[f][k] (256-k rows), out[(w*Hdim+h)*256+f] += bias[h*256+f]
// m = h*400 + w
__global__ __launch_bounds__(256) void gemmT_kernel(
    const float* __restrict__ A, int Astride,
    const float* __restrict__ Wt, const float* __restrict__ bias,
    float* __restrict__ Cout, int Hdim)
{
  __shared__ float As[16][64];
  __shared__ float Ws[16][65];
  int m0 = blockIdx.x * 64;
  int n0 = blockIdx.y * 64;
  int tid = threadIdx.x;
  int tx = tid & 15, ty = tid >> 4;
  float acc[4][4] = {};
  for (int k0 = 0; k0 < 256; k0 += 16) {
    {
      int r = tid >> 4;            // k row 0..15
      int cq = (tid & 15) << 2;    // m col
      float4 v = *(const float4*)(A + (size_t)(k0 + r) * Astride + m0 + cq);
      *(float4*)(&As[r][cq]) = v;
    }
    {
      int f = tid >> 2;            // 0..63
      int kq = (tid & 3) << 2;
      float4 v = *(const float4*)(Wt + (size_t)(n0 + f) * 256 + k0 + kq);
      Ws[kq + 0][f] = v.x; Ws[kq + 1][f] = v.y;
      Ws[kq + 2][f] = v.z; Ws[kq + 3][f] = v.w;
    }
    __syncthreads();
#pragma unroll
    for (int kk = 0; kk < 16; ++kk) {
      float a[4], b[4];
#pragma unroll
      for (int i = 0; i < 4; ++i) a[i] = As[kk][ty * 4 + i];
#pragma unroll
      for (int jj = 0; jj < 4; ++jj) b[jj] = Ws[kk][tx * 4 + jj];
#pragma unroll
      for (int i = 0; i < 4; ++i)
#pragma unroll
        for (int jj = 0; jj < 4; ++jj) acc[i][jj] += a[i] * b[jj];
    }
    __syncthreads();
  }
#pragma unroll
  for (int i = 0; i < 4; ++i) {
    int m = m0 + ty * 4 + i;
    int h = m / 400;
    int w = m - h * 400;
    size_t obase = (size_t)(w * Hdim + h) * 256;
    int f = n0 + tx * 4;
    float4 bv = *(const float4*)(bias + h * 256 + f);
    float4 ov;
    ov.x = acc[i][0] + bv.x; ov.y = acc[i][1] + bv.y;
    ov.z = acc[i][2] + bv.z; ov.w = acc[i][3] + bv.w;
    *(float4*)(Cout + obase + f) = ov;
  }
}

// ===================== GEMM (A M-major): C = A * W^T =====================
// mode 0: Cout[m*256+f] = acc + biasf[f]
// mode 2: Cout[m*256+f] = acc
__global__ __launch_bounds__(256) void gemmN_kernel(
    const float* __restrict__ A, const float* __restrict__ Wt,
    const float* __restrict__ biasf, float* __restrict__ Cout, int mode)
{
  __shared__ float As[64][17];
  __shared__ float Ws[16][65];
  int m0 = blockIdx.x * 64;
  int n0 = blockIdx.y * 64;
  int tid = threadIdx.x;
  int tx = tid & 15, ty = tid >> 4;
  float acc[4][4] = {};
  for (int k0 = 0; k0 < 256; k0 += 16) {
    {
      int m = tid >> 2;            // 0..63
      int kq = (tid & 3) << 2;
      float4 v = *(const float4*)(A + (size_t)(m0 + m) * 256 + k0 + kq);
      As[m][kq + 0] = v.x; As[m][kq + 1] = v.y;
      As[m][kq + 2] = v.z; As[m][kq + 3] = v.w;
    }
    {
      int f = tid >> 2;
      int kq = (tid & 3) << 2;
      float4 v = *(const float4*)(Wt + (size_t)(n0 + f) * 256 + k0 + kq);
      Ws[kq + 0][f] = v.x; Ws[kq + 1][f] = v.y;
      Ws[kq + 2][f] = v.z; Ws[kq + 3][f] = v.w;
    }
    __syncthreads();
#pragma unroll
    for (int kk = 0; kk < 16; ++kk) {
      float a[4], b[4];
#pragma unroll
      for (int i = 0; i < 4; ++i) a[i] = As[ty * 4 + i][kk];
#pragma unroll
      for (int jj = 0; jj < 4; ++jj) b[jj] = Ws[kk][tx * 4 + jj];
#pragma unroll
      for (int i = 0; i < 4; ++i)
#pragma unroll
        for (int jj = 0; jj < 4; ++jj) acc[i][jj] += a[i] * b[jj];
    }
    __syncthreads();
  }
#pragma unroll
  for (int i = 0; i < 4; ++i) {
    int m = m0 + ty * 4 + i;
    int f = n0 + tx * 4;
    float4 ov;
    if (mode == 0) {
      float4 bv = *(const float4*)(biasf + f);
      ov.x = acc[i][0] + bv.x; ov.y = acc[i][1] + bv.y;
      ov.z = acc[i][2] + bv.z; ov.w = acc[i][3] + bv.w;
    } else {
      ov.x = acc[i][0]; ov.y = acc[i][1];
      ov.z = acc[i][2]; ov.w = acc[i][3];
    }
    *(float4*)(Cout + (size_t)m * 256 + f) = ov;
  }
}

// ===================== GEMM A[m][k] * B[k][n] (effective weights) ==========
__global__ __launch_bounds__(256) void gemm_ab_kernel(
    const float* __restrict__ in_w, const float* __restrict__ Wq,
    const float* __restrict__ Wk, const float* __restrict__ Wv,
    float* __restrict__ weff)
{
  int z = blockIdx.z;
  const float* A = in_w + (size_t)z * 65536;
  const float* B = (z == 0) ? Wq : ((z == 1) ? Wk : Wv);
  float* C = weff + (size_t)z * 65536;
  __shared__ float As[64][17];
  __shared__ float Bs[16][64];
  int m0 = blockIdx.x * 64;
  int n0 = blockIdx.y * 64;
  int tid = threadIdx.x;
  int tx = tid & 15, ty = tid >> 4;
  float acc[4][4] = {};
  for (int k0 = 0; k0 < 256; k0 += 16) {
    {
      int m = tid >> 2;
      int kq = (tid & 3) << 2;
      float4 v = *(const float4*)(A + (size_t)(m0 + m) * 256 + k0 + kq);
      As[m][kq + 0] = v.x; As[m][kq + 1] = v.y;
      As[m][kq + 2] = v.z; As[m][kq + 3] = v.w;
    }
    {
      int k = tid >> 4;
      int nq = (tid & 15) << 2;
      float4 v = *(const float4*)(B + (size_t)(k0 + k) * 256 + n0 + nq);
      *(float4*)(&Bs[k][nq]) = v;
    }
    __syncthreads();
#pragma unroll
    for (int kk = 0; kk < 16; ++kk) {
      float a[4], b[4];
#pragma unroll
      for (int i = 0; i < 4; ++i) a[i] = As[ty * 4 + i][kk];
#pragma unroll
      for (int jj = 0; jj < 4; ++jj) b[jj] = Bs[kk][tx * 4 + jj];
#pragma unroll
      for (int i = 0; i < 4; ++i)
#pragma unroll
        for (int jj = 0; jj < 4; ++jj) acc[i][jj] += a[i] * b[jj];
    }
    __syncthreads();
  }
#pragma unroll
  for (int i = 0; i < 4; ++i) {
    int m = m0 + ty * 4 + i;
    *(float4*)(C + (size_t)m * 256 + n0 + tx * 4) = *(float4*)&acc[i][0];
  }
}

// ===================== effective biases =====================
__global__ void beff_kernel(const float* __restrict__ in_w, const float* __restrict__ in_b,
                            const float* __restrict__ bq, const float* __restrict__ bk,
                            const float* __restrict__ bv, float* __restrict__ beff)
{
  int z = blockIdx.x;
  int f = threadIdx.x;
  const float* bsrc = (z == 0) ? bq : ((z == 1) ? bk : bv);
  const float* row = in_w + (size_t)(z * 256 + f) * 256;
  float acc = in_b[z * 256 + f];
  for (int e = 0; e < 256; ++e) acc += row[e] * bsrc[e];
  beff[z * 256 + f] = acc;
}

// ===================== attention =====================
// per-block: one (b,head); 128 threads = one query row each
__global__ __launch_bounds__(128) void attn_kernel(
    const float* __restrict__ qq, const float* __restrict__ kk,
    const float* __restrict__ vv, float* __restrict__ obuf)
{
  int b = blockIdx.x >> 3;
  int hd = blockIdx.x & 7;
  __shared__ float ks[64][32];
  __shared__ float vs[64][32];
  int t = threadIdx.x;
#pragma unroll
  for (int i = 0; i < 16; ++i) {
    int e = i * 128 + t;
    int ki = e >> 5, d = e & 31;
    ks[ki][d] = kk[(size_t)(b * 64 + ki) * 256 + hd * 32 + d];
    vs[ki][d] = vv[(size_t)(b * 64 + ki) * 256 + hd * 32 + d];
  }
  __syncthreads();
  float qr[32];
  const float* qp = qq + (size_t)(b * 128 + t) * 256 + hd * 32;
#pragma unroll
  for (int d = 0; d < 32; d += 4) {
    float4 v = *(const float4*)(qp + d);
    qr[d] = v.x; qr[d + 1] = v.y; qr[d + 2] = v.z; qr[d + 3] = v.w;
  }
  float s[64];
  float mx = -1e30f;
  const float scale = 0.17677669529663687f;   // 1/sqrt(32)
#pragma unroll
  for (int ki = 0; ki < 64; ++ki) {
    const float4* kr = (const float4*)(&ks[ki][0]);
    float acc = 0.0f;
#pragma unroll
    for (int q4 = 0; q4 < 8; ++q4) {
      float4 kv = kr[q4];
      acc += qr[q4 * 4 + 0] * kv.x + qr[q4 * 4 + 1] * kv.y
           + qr[q4 * 4 + 2] * kv.z + qr[q4 * 4 + 3] * kv.w;
    }
    acc *= scale;
    s[ki] = acc;
    mx = fmaxf(mx, acc);
  }
  float l = 0.0f;
#pragma unroll
  for (int ki = 0; ki < 64; ++ki) { s[ki] = __expf(s[ki] - mx); l += s[ki]; }
  float invl = 1.0f / l;
  float o[32];
#pragma unroll
  for (int d = 0; d < 32; ++d) o[d] = 0.0f;
#pragma unroll
  for (int ki = 0; ki < 64; ++ki) {
    float p = s[ki];
    const float4* vr = (const float4*)(&vs[ki][0]);
#pragma unroll
    for (int d4 = 0; d4 < 8; ++d4) {
      float4 v4 = vr[d4];
      o[d4 * 4 + 0] += p * v4.x; o[d4 * 4 + 1] += p * v4.y;
      o[d4 * 4 + 2] += p * v4.z; o[d4 * 4 + 3] += p * v4.w;
    }
  }
  float* op = obuf + (size_t)(b * 128 + t) * 256 + hd * 32;
#pragma unroll
  for (int d = 0; d < 32; d += 4) {
    float4 v;
    v.x = o[d] * invl; v.y = o[d + 1] * invl;
    v.z = o[d + 2] * invl; v.w = o[d + 3] * invl;
    *(float4*)(op + d) = v;
  }
}

// ===================== per-pixel gather-reduce of attention outputs ========
// osum[p][c] = sum over samples mapping to pixel p of obuf[m][c]
__global__ __launch_bounds__(256) void gather_kernel(
    const float* __restrict__ obuf, const int* __restrict__ order,
    const int* __restrict__ offsets, const float* __restrict__ cnt,
    float* __restrict__ osum)
{
  int p = blockIdx.x;
  int c = threadIdx.x;
  int off = offsets[p];
  int n = (int)cnt[p];
  float acc = 0.0f, acc2 = 0.0f;
  int i = 0;
  for (; i + 2 <= n; i += 2) {
    int m0 = order[off + i], m1 = order[off + i + 1];
    acc  += obuf[(size_t)m0 * 256 + c];
    acc2 += obuf[(size_t)m1 * 256 + c];
  }
  if (i < n) acc += obuf[(size_t)order[off + i] * 256 + c];
  osum[(size_t)p * 256 + c] = acc + acc2;
}

// ===================== residual update / final (with LDS transpose) ========
// enh[p][c] -> a_cur[c][p] (+=) or out[c][p] = a_cur + 2*enh
// val = (enhpre[p][c] + cnt[p]*out_b[c]) / max(cnt[p],1)
__global__ __launch_bounds__(256) void update_kernel(
    float* __restrict__ a_cur, const float* __restrict__ enhpre,
    const float* __restrict__ cnt, const float* __restrict__ out_b,
    float* __restrict__ outp, int final_mode)
{
  __shared__ float tile[16][260];
  __shared__ float obs[256];
  __shared__ float cn[16];
  __shared__ float rin[16];
  int p0 = blockIdx.x * 16;
  int t = threadIdx.x;
  obs[t] = out_b[t];
  if (t < 16) {
    float c = cnt[p0 + t];
    cn[t] = c;
    rin[t] = 1.0f / fmaxf(c, 1.0f);
  }
#pragma unroll
  for (int q = 0; q < 4; ++q) {
    int l = q * 256 + t;        // 0..1023 float4 slots (16 rows x 64)
    int row = l >> 6;
    int col = (l & 63) << 2;
    float4 v = *(const float4*)(enhpre + (size_t)(p0 + row) * 256 + col);
    tile[row][col] = v.x; tile[row][col + 1] = v.y;
    tile[row][col + 2] = v.z; tile[row][col + 3] = v.w;
  }
  __syncthreads();
  int pl = t & 15;
  int c0 = t >> 4;
#pragma unroll
  for (int cc = 0; cc < 16; ++cc) {
    int ch = cc * 16 + c0;
    float val = (tile[pl][ch] + cn[pl] * obs[ch]) * rin[pl];
    size_t ai = (size_t)ch * PIX + p0 + pl;
    if (final_mode) outp[ai] = a_cur[ai] + 2.0f * val;
    else            a_cur[ai] += val;
  }
}

// ===================== launch =====================
extern "C" void kernel_launch(void* const* d_in, const int* in_sizes, int n_in,
                              void* d_out, int out_size, void* d_ws, size_t ws_size,
                              hipStream_t stream) {
  const float* list_a = (const float*)d_in[0];
  const float* list_b = (const float*)d_in[1];
  const float* rots   = (const float*)d_in[3];
  const float* fxs    = (const float*)d_in[5];
  const float* cxs    = (const float*)d_in[6];
  const float* pos_a  = (const float*)d_in[7];
  const float* pos_b  = (const float*)d_in[8];
  const float* Wq     = (const float*)d_in[9];
  const float* bq     = (const float*)d_in[10];
  const float* Wk     = (const float*)d_in[11];
  const float* bk     = (const float*)d_in[12];
  const float* Wv     = (const float*)d_in[13];
  const float* bv     = (const float*)d_in[14];
  const float* in_w   = (const float*)d_in[15];
  const float* in_b   = (const float*)d_in[16];
  const float* out_w  = (const float*)d_in[17];
  const float* out_b  = (const float*)d_in[18];

  float* ws     = (float*)d_ws;
  float* weff   = ws;                       // 196608
  float* beff   = weff + 196608;            // 768
  float* qpos   = beff + 768;               // 32768
  float* kpos   = qpos + 32768;             // 16384
  float* vpos   = kpos + 16384;             // 16384
  float* a_cur  = vpos + 16384;             // 4194304
  float* xarr   = a_cur + 4194304;          // 51200
  float* yarr   = xarr + 51200;             // 51200
  int*   idxarr = (int*)(yarr + 51200);     // 51200
  float* cnt    = (float*)(idxarr + 51200); // 16384
  int*   cursor = (int*)(cnt + 16384);      // 16384 (contiguous with cnt: one memset)
  int*   offs   = cursor + 16384;           // 16384
  int*   order  = offs + 16384;             // 51200
  float* a_rect = (float*)(order + 51200);  // 13107200 (doubles as attention o-buffer)
  float* qq     = a_rect + 13107200;        // 13107200
  float* kkb    = qq + 13107200;            // 6553600
  float* vvb    = kkb + 6553600;            // 6553600
  float* osum   = qq;    // alias: qq is dead after attention
  float* enhpre = kkb;   // alias: kkb is dead after attention

  hipMemcpyAsync(a_cur, list_a, (size_t)4194304 * sizeof(float),
                 hipMemcpyDeviceToDevice, stream);

  // effective weights + biases (tiny)
  gemm_ab_kernel<<<dim3(4, 4, 3), 256, 0, stream>>>(in_w, Wq, Wk, Wv, weff);
  beff_kernel<<<3, 256, 0, stream>>>(in_w, in_b, bq, bk, bv, beff);

  // positional bias tables: pos @ Weff^T + beff
  gemmN_kernel<<<dim3(2, 4), 256, 0, stream>>>(pos_a, weff, beff, qpos, 0);
  gemmN_kernel<<<dim3(1, 4), 256, 0, stream>>>(pos_b, weff + 65536, beff + 256, kpos, 0);
  gemmN_kernel<<<dim3(1, 4), 256, 0, stream>>>(pos_b, weff + 131072, beff + 512, vpos, 0);

  for (int jj = 0; jj < 2; ++jj) {
    int j = jj ? 3 : 0;
    hipMemsetAsync(cnt, 0, (size_t)2 * 16384 * sizeof(float), stream);  // cnt + cursor
    coords_kernel<<<200, 256, 0, stream>>>(rots, fxs, cxs, j, xarr, yarr, idxarr, cnt);
    prefix_kernel<<<1, 256, 0, stream>>>(cnt, offs);
    fill_kernel<<<200, 256, 0, stream>>>(idxarr, offs, cursor, order);
    sample_kernel<<<dim3(200, 256), 256, 0, stream>>>(a_cur, xarr, yarr, a_rect);
    // qq = (a_rect + pos) @ Wq_eff^T : A K-major
    gemmT_kernel<<<dim3(800, 4), 256, 0, stream>>>(a_rect, MS, weff, qpos, qq, 128);
    const float* bsrc = list_b + (size_t)j * 6553600;
    gemmT_kernel<<<dim3(400, 4), 256, 0, stream>>>(bsrc, MB, weff + 65536, kpos, kkb, 64);
    gemmT_kernel<<<dim3(400, 4), 256, 0, stream>>>(bsrc, MB, weff + 131072, vpos, vvb, 64);
    attn_kernel<<<3200, 128, 0, stream>>>(qq, kkb, vvb, a_rect);   // o into a_rect
    // per-pixel reduction of o, then single out-proj GEMM on 16384 rows
    gather_kernel<<<16384, 256, 0, stream>>>(a_rect, order, offs, cnt, osum);
    gemmN_kernel<<<dim3(256, 4), 256, 0, stream>>>(osum, out_w, nullptr, enhpre, 2);
    update_kernel<<<1024, 256, 0, stream>>>(a_cur, enhpre, cnt, out_b,
                                            jj ? (float*)d_out : nullptr, jj);
  }
}

// Round 3
// 1163.985 us; speedup vs baseline: 2.1977x; 1.2867x over previous
//
#include <hip/hip_runtime.h>

// Problem constants
// a: (256,128,128)  b: (4,256,64,400)  E=256 NH=8 DH=32  B=400 Lq=128 Lk=64
#define PIX 16384          // 128*128
#define MS 51200           // H1*W2 samples
#define MB 25600           // H2*W2

typedef __attribute__((ext_vector_type(8))) short short8;
typedef __attribute__((ext_vector_type(4))) float floatx4;

__device__ inline ushort f2b(float x) {
  uint u = __float_as_uint(x);
  return (ushort)((u + 0x7fffu + ((u >> 16) & 1u)) >> 16);
}

// ===================== coords: x,y, scatter idx, counts =====================
__global__ __launch_bounds__(256) void coords_kernel(
    const float* __restrict__ rots, const float* __restrict__ fxs,
    const float* __restrict__ cxs, int j,
    float* __restrict__ xarr, float* __restrict__ yarr,
    int* __restrict__ idxarr, float* __restrict__ cnt)
{
  int s = blockIdx.x * 256 + threadIdx.x;      // 0..51199, s = h*400 + w
  int h = s / 400;
  int w = s - h * 400;
  float fx = fxs[j], cx = cxs[j];
  const float* R = rots + j * 9;
  float cr = R[3];        // rots[1][0]
  float sr = -R[0];       // -rots[0][0]
  float t = (2.0f * (float)w + 1.0f - cx) / fx;      // tan(ang)
  float inv = 1.0f / sqrtf(1.0f + t * t);            // cos(ang)
  float ca = (cr + sr * t) * inv;                    // cr*cos + sr*sin
  float sa = (cr * t - sr) * inv;                    // -sr*cos + cr*sin
  float rad = ((float)h * (1.0f / 127.0f)) * 90.50966799187808f;
  float x = 64.0f + rad * ca;
  float y = 64.0f - rad * sa;
  xarr[s] = x;
  yarr[s] = y;
  int xi = (int)fminf(fmaxf(rintf(x), 0.0f), 127.0f);
  int yi = (int)fminf(fmaxf(rintf(y), 0.0f), 127.0f);
  int pix = yi * 128 + xi;
  idxarr[s] = pix;
  atomicAdd(&cnt[pix], 1.0f);
}

// ===================== prefix scan over pixel counts =====================
__global__ __launch_bounds__(256) void prefix_kernel(
    const float* __restrict__ cnt, int* __restrict__ offsets)
{
  __shared__ int sh[256];
  int t = threadIdx.x;
  int base = t * 64;
  int sum = 0;
  for (int i = 0; i < 64; ++i) sum += (int)cnt[base + i];
  sh[t] = sum;
  __syncthreads();
  for (int d = 1; d < 256; d <<= 1) {
    int v = (t >= d) ? sh[t - d] : 0;
    __syncthreads();
    sh[t] += v;
    __syncthreads();
  }
  int run = sh[t] - sum;   // exclusive prefix for this thread's chunk
  for (int i = 0; i < 64; ++i) {
    offsets[base + i] = run;
    run += (int)cnt[base + i];
  }
}

// ===================== fill sorted sample lists =====================
__global__ __launch_bounds__(256) void fill_kernel(
    const int* __restrict__ idxarr, const int* __restrict__ offsets,
    int* __restrict__ cursor, int* __restrict__ order)
{
  int s = blockIdx.x * 256 + threadIdx.x;
  int pix = idxarr[s];
  int pos = offsets[pix] + atomicAdd(&cursor[pix], 1);
  // store the attention-output row index m = w*128 + h  (s = h*400 + w)
  order[pos] = (s % 400) * 128 + (s / 400);
}

// ===================== bilinear sampler: a_recth[c][s] (bf16) ==============
__global__ __launch_bounds__(256) void sample_kernel(
    const float* __restrict__ a_cur, const float* __restrict__ xarr,
    const float* __restrict__ yarr, ushort* __restrict__ a_recth)
{
  int s = blockIdx.x * 256 + threadIdx.x;   // sample index
  int c = blockIdx.y;                       // channel
  float x = fminf(fmaxf(xarr[s], 0.0f), 127.0f);
  float y = fminf(fmaxf(yarr[s], 0.0f), 127.0f);
  float x0f = floorf(x), y0f = floorf(y);
  int x0 = (int)x0f, y0 = (int)y0f;
  int x1 = min(x0 + 1, 127), y1 = min(y0 + 1, 127);
  float wx = x - x0f, wy = y - y0f;
  const float* img = a_cur + (size_t)c * PIX;
  float v00 = img[y0 * 128 + x0];
  float v01 = img[y0 * 128 + x1];
  float v10 = img[y1 * 128 + x0];
  float v11 = img[y1 * 128 + x1];
  float val = v00 * (1.0f - wx) * (1.0f - wy) + v01 * wx * (1.0f - wy)
            + v10 * (1.0f - wx) * wy + v11 * wx * wy;
  a_recth[(size_t)c * MS + s] = f2b(val);
}

// ===================== f32 -> bf16 bulk convert (float4-wide) ==============
__global__ __launch_bounds__(256) void f2b_kernel(
    const float* __restrict__ in, ushort* __restrict__ out)
{
  int t = blockIdx.x * 256 + threadIdx.x;
  float4 v = ((const float4*)in)[t];
  ushort4 o;
  o.x = f2b(v.x); o.y = f2b(v.y); o.z = f2b(v.z); o.w = f2b(v.w);
  ((ushort4*)out)[t] = o;
}

// ===================== MFMA GEMM: C = A^T(K-major bf16) @ W^T(bf16) ========
// Ah[k][m] stride Astride; Wh[f][k] (k contiguous); bias fp32 [h][256];
// out row permute: m = h*400+w  ->  row = w*Hdim+h;  Cout[row*256+f] fp32
#define BKP 144   // LDS A row stride in halfs (k-row -> 128 m + swizzle pad)
#define WKP 40    // LDS W row stride in halfs (32 k + pad)
__global__ __launch_bounds__(256) void mfma_gemmT_kernel(
    const ushort* __restrict__ Ah, int Astride,
    const ushort* __restrict__ Wh, const float* __restrict__ bias,
    float* __restrict__ Cout, int Hdim)
{
  __shared__ ushort lA[32 * BKP];   // [k_local][m' (xor-swizzled)]
  __shared__ ushort lW[128 * WKP];  // [f_local][k_local]
  int m0 = blockIdx.x * 128;
  int n0 = blockIdx.y * 128;
  int tid = threadIdx.x;
  int lane = tid & 63;
  int wave = tid >> 6;
  int col = lane & 15;
  int quad = lane >> 4;
  int sw = (wave & 1) * 64;     // wave sample-offset in tile
  int fw = (wave >> 1) * 64;    // wave feature-offset in tile
  floatx4 acc[4][4];
#pragma unroll
  for (int i = 0; i < 4; ++i)
#pragma unroll
    for (int jx = 0; jx < 4; ++jx) acc[i][jx] = (floatx4){0.f, 0.f, 0.f, 0.f};

  for (int kb = 0; kb < 256; kb += 32) {
    // stage A-tile: 32 k-rows x 128 m halfs, xor-swizzle m by 16*(k>>3)
#pragma unroll
    for (int half = 0; half < 2; ++half) {
      int L = tid + half * 256;
      int r = L >> 4;            // k row 0..31
      int c = L & 15;            // 16-byte m chunk
      uint4 v = *(const uint4*)(Ah + (size_t)(kb + r) * Astride + m0 + c * 8);
      int mp = (c * 8) ^ ((r >> 3) * 16);
      *(uint4*)&lA[r * BKP + mp] = v;
    }
    // stage W-tile: 128 f-rows x 32 k halfs
#pragma unroll
    for (int half = 0; half < 2; ++half) {
      int L = tid + half * 256;
      int f = L >> 2;            // 0..127
      int seg = L & 3;           // 8-half chunk of k
      uint4 v = *(const uint4*)(Wh + (size_t)(n0 + f) * 256 + kb + seg * 8);
      *(uint4*)&lW[f * WKP + seg * 8] = v;
    }
    __syncthreads();
    short8 aop[4];
#pragma unroll
    for (int tf = 0; tf < 4; ++tf) {
      int fr = fw + tf * 16 + col;
      aop[tf] = *(const short8*)&lW[fr * WKP + quad * 8];
    }
#pragma unroll
    for (int ts = 0; ts < 4; ++ts) {
      int mi = sw + ts * 16 + col;
      int mp = mi ^ (quad * 16);
      short8 bop;
#pragma unroll
      for (int jx = 0; jx < 8; ++jx)
        bop[jx] = (short)lA[(quad * 8 + jx) * BKP + mp];
#pragma unroll
      for (int tf = 0; tf < 4; ++tf)
        acc[ts][tf] = __builtin_amdgcn_mfma_f32_16x16x32_bf16(
            aop[tf], bop, acc[ts][tf], 0, 0, 0);
    }
    __syncthreads();
  }
  // epilogue: D col=lane&15 -> sample, row=quad*4+reg -> feature
#pragma unroll
  for (int ts = 0; ts < 4; ++ts) {
    int m = m0 + sw + ts * 16 + col;
    int h = m / 400;
    int w = m - h * 400;
    size_t obase = (size_t)(w * Hdim + h) * 256;
#pragma unroll
    for (int tf = 0; tf < 4; ++tf) {
      int f = n0 + fw + tf * 16 + quad * 4;
      float4 bv = *(const float4*)(bias + h * 256 + f);
      float4 ov;
      ov.x = acc[ts][tf][0] + bv.x;
      ov.y = acc[ts][tf][1] + bv.y;
      ov.z = acc[ts][tf][2] + bv.z;
      ov.w = acc[ts][tf][3] + bv.w;
      *(float4*)(Cout + obase + f) = ov;
    }
  }
}

// ===================== GEMM (A M-major fp32): C = A * W^T ==================
// mode 0: Cout[m*256+f] = acc + biasf[f];  mode 2: Cout[m*256+f] = acc
__global__ __launch_bounds__(256) void gemmN_kernel(
    const float* __restrict__ A, const float* __restrict__ Wt,
    const float* __restrict__ biasf, float* __restrict__ Cout, int mode)
{
  __shared__ float As[64][17];
  __shared__ float Ws[16][65];
  int m0 = blockIdx.x * 64;
  int n0 = blockIdx.y * 64;
  int tid = threadIdx.x;
  int tx = tid & 15, ty = tid >> 4;
  float acc[4][4] = {};
  for (int k0 = 0; k0 < 256; k0 += 16) {
    {
      int m = tid >> 2;            // 0..63
      int kq = (tid & 3) << 2;
      float4 v = *(const float4*)(A + (size_t)(m0 + m) * 256 + k0 + kq);
      As[m][kq + 0] = v.x; As[m][kq + 1] = v.y;
      As[m][kq + 2] = v.z; As[m][kq + 3] = v.w;
    }
    {
      int f = tid >> 2;
      int kq = (tid & 3) << 2;
      float4 v = *(const float4*)(Wt + (size_t)(n0 + f) * 256 + k0 + kq);
      Ws[kq + 0][f] = v.x; Ws[kq + 1][f] = v.y;
      Ws[kq + 2][f] = v.z; Ws[kq + 3][f] = v.w;
    }
    __syncthreads();
#pragma unroll
    for (int kk = 0; kk < 16; ++kk) {
      float a[4], b[4];
#pragma unroll
      for (int i = 0; i < 4; ++i) a[i] = As[ty * 4 + i][kk];
#pragma unroll
      for (int jj = 0; jj < 4; ++jj) b[jj] = Ws[kk][tx * 4 + jj];
#pragma unroll
      for (int i = 0; i < 4; ++i)
#pragma unroll
        for (int jj = 0; jj < 4; ++jj) acc[i][jj] += a[i] * b[jj];
    }
    __syncthreads();
  }
#pragma unroll
  for (int i = 0; i < 4; ++i) {
    int m = m0 + ty * 4 + i;
    int f = n0 + tx * 4;
    float4 ov;
    if (mode == 0) {
      float4 bv = *(const float4*)(biasf + f);
      ov.x = acc[i][0] + bv.x; ov.y = acc[i][1] + bv.y;
      ov.z = acc[i][2] + bv.z; ov.w = acc[i][3] + bv.w;
    } else {
      ov.x = acc[i][0]; ov.y = acc[i][1];
      ov.z = acc[i][2]; ov.w = acc[i][3];
    }
    *(float4*)(Cout + (size_t)m * 256 + f) = ov;
  }
}

// ===================== GEMM A[m][k] * B[k][n] (effective weights) ==========
__global__ __launch_bounds__(256) void gemm_ab_kernel(
    const float* __restrict__ in_w, const float* __restrict__ Wq,
    const float* __restrict__ Wk, const float* __restrict__ Wv,
    float* __restrict__ weff)
{
  int z = blockIdx.z;
  const float* A = in_w + (size_t)z * 65536;
  const float* B = (z == 0) ? Wq : ((z == 1) ? Wk : Wv);
  float* C = weff + (size_t)z * 65536;
  __shared__ float As[64][17];
  __shared__ float Bs[16][64];
  int m0 = blockIdx.x * 64;
  int n0 = blockIdx.y * 64;
  int tid = threadIdx.x;
  int tx = tid & 15, ty = tid >> 4;
  float acc[4][4] = {};
  for (int k0 = 0; k0 < 256; k0 += 16) {
    {
      int m = tid >> 2;
      int kq = (tid & 3) << 2;
      float4 v = *(const float4*)(A + (size_t)(m0 + m) * 256 + k0 + kq);
      As[m][kq + 0] = v.x; As[m][kq + 1] = v.y;
      As[m][kq + 2] = v.z; As[m][kq + 3] = v.w;
    }
    {
      int k = tid >> 4;
      int nq = (tid & 15) << 2;
      float4 v = *(const float4*)(B + (size_t)(k0 + k) * 256 + n0 + nq);
      *(float4*)(&Bs[k][nq]) = v;
    }
    __syncthreads();
#pragma unroll
    for (int kk = 0; kk < 16; ++kk) {
      float a[4], b[4];
#pragma unroll
      for (int i = 0; i < 4; ++i) a[i] = As[ty * 4 + i][kk];
#pragma unroll
      for (int jj = 0; jj < 4; ++jj) b[jj] = Bs[kk][tx * 4 + jj];
#pragma unroll
      for (int i = 0; i < 4; ++i)
#pragma unroll
        for (int jj = 0; jj < 4; ++jj) acc[i][jj] += a[i] * b[jj];
    }
    __syncthreads();
  }
#pragma unroll
  for (int i = 0; i < 4; ++i) {
    int m = m0 + ty * 4 + i;
    *(float4*)(C + (size_t)m * 256 + n0 + tx * 4) = *(float4*)&acc[i][0];
  }
}

// ===================== effective biases =====================
__global__ void beff_kernel(const float* __restrict__ in_w, const float* __restrict__ in_b,
                            const float* __restrict__ bq, const float* __restrict__ bk,
                            const float* __restrict__ bv, float* __restrict__ beff)
{
  int z = blockIdx.x;
  int f = threadIdx.x;
  const float* bsrc = (z == 0) ? bq : ((z == 1) ? bk : bv);
  const float* row = in_w + (size_t)(z * 256 + f) * 256;
  float acc = in_b[z * 256 + f];
  for (int e = 0; e < 256; ++e) acc += row[e] * bsrc[e];
  beff[z * 256 + f] = acc;
}

// ===================== attention (in-place: obuf may alias qq) =============
__global__ __launch_bounds__(128) void attn_kernel(
    const float* __restrict__ qq, const float* __restrict__ kk,
    const float* __restrict__ vv, float* __restrict__ obuf)
{
  int b = blockIdx.x >> 3;
  int hd = blockIdx.x & 7;
  __shared__ float ks[64][32];
  __shared__ float vs[64][32];
  int t = threadIdx.x;
#pragma unroll
  for (int i = 0; i < 16; ++i) {
    int e = i * 128 + t;
    int ki = e >> 5, d = e & 31;
    ks[ki][d] = kk[(size_t)(b * 64 + ki) * 256 + hd * 32 + d];
    vs[ki][d] = vv[(size_t)(b * 64 + ki) * 256 + hd * 32 + d];
  }
  __syncthreads();
  float qr[32];
  const float* qp = qq + (size_t)(b * 128 + t) * 256 + hd * 32;
#pragma unroll
  for (int d = 0; d < 32; d += 4) {
    float4 v = *(const float4*)(qp + d);
    qr[d] = v.x; qr[d + 1] = v.y; qr[d + 2] = v.z; qr[d + 3] = v.w;
  }
  float s[64];
  float mx = -1e30f;
  const float scale = 0.17677669529663687f;   // 1/sqrt(32)
#pragma unroll
  for (int ki = 0; ki < 64; ++ki) {
    const float4* kr = (const float4*)(&ks[ki][0]);
    float acc = 0.0f;
#pragma unroll
    for (int q4 = 0; q4 < 8; ++q4) {
      float4 kv = kr[q4];
      acc += qr[q4 * 4 + 0] * kv.x + qr[q4 * 4 + 1] * kv.y
           + qr[q4 * 4 + 2] * kv.z + qr[q4 * 4 + 3] * kv.w;
    }
    acc *= scale;
    s[ki] = acc;
    mx = fmaxf(mx, acc);
  }
  float l = 0.0f;
#pragma unroll
  for (int ki = 0; ki < 64; ++ki) { s[ki] = __expf(s[ki] - mx); l += s[ki]; }
  float invl = 1.0f / l;
  float o[32];
#pragma unroll
  for (int d = 0; d < 32; ++d) o[d] = 0.0f;
#pragma unroll
  for (int ki = 0; ki < 64; ++ki) {
    float p = s[ki];
    const float4* vr = (const float4*)(&vs[ki][0]);
#pragma unroll
    for (int d4 = 0; d4 < 8; ++d4) {
      float4 v4 = vr[d4];
      o[d4 * 4 + 0] += p * v4.x; o[d4 * 4 + 1] += p * v4.y;
      o[d4 * 4 + 2] += p * v4.z; o[d4 * 4 + 3] += p * v4.w;
    }
  }
  float* op = obuf + (size_t)(b * 128 + t) * 256 + hd * 32;
#pragma unroll
  for (int d = 0; d < 32; d += 4) {
    float4 v;
    v.x = o[d] * invl; v.y = o[d + 1] * invl;
    v.z = o[d + 2] * invl; v.w = o[d + 3] * invl;
    *(float4*)(op + d) = v;
  }
}

// ===================== per-pixel gather-reduce of attention outputs ========
__global__ __launch_bounds__(256) void gather_kernel(
    const float* __restrict__ obuf, const int* __restrict__ order,
    const int* __restrict__ offsets, const float* __restrict__ cnt,
    float* __restrict__ osum)
{
  int p = blockIdx.x;
  int c = threadIdx.x;
  int off = offsets[p];
  int n = (int)cnt[p];
  float acc = 0.0f, acc2 = 0.0f;
  int i = 0;
  for (; i + 2 <= n; i += 2) {
    int m0 = order[off + i], m1 = order[off + i + 1];
    acc  += obuf[(size_t)m0 * 256 + c];
    acc2 += obuf[(size_t)m1 * 256 + c];
  }
  if (i < n) acc += obuf[(size_t)order[off + i] * 256 + c];
  osum[(size_t)p * 256 + c] = acc + acc2;
}

// ===================== residual update / final (with LDS transpose) ========
__global__ __launch_bounds__(256) void update_kernel(
    float* __restrict__ a_cur, const float* __restrict__ enhpre,
    const float* __restrict__ cnt, const float* __restrict__ out_b,
    float* __restrict__ outp, int final_mode)
{
  __shared__ float tile[16][260];
  __shared__ float obs[256];
  __shared__ float cn[16];
  __shared__ float rin[16];
  int p0 = blockIdx.x * 16;
  int t = threadIdx.x;
  obs[t] = out_b[t];
  if (t < 16) {
    float c = cnt[p0 + t];
    cn[t] = c;
    rin[t] = 1.0f / fmaxf(c, 1.0f);
  }
#pragma unroll
  for (int q = 0; q < 4; ++q) {
    int l = q * 256 + t;
    int row = l >> 6;
    int colq = (l & 63) << 2;
    float4 v = *(const float4*)(enhpre + (size_t)(p0 + row) * 256 + colq);
    tile[row][colq] = v.x; tile[row][colq + 1] = v.y;
    tile[row][colq + 2] = v.z; tile[row][colq + 3] = v.w;
  }
  __syncthreads();
  int pl = t & 15;
  int c0 = t >> 4;
#pragma unroll
  for (int cc = 0; cc < 16; ++cc) {
    int ch = cc * 16 + c0;
    float val = (tile[pl][ch] + cn[pl] * obs[ch]) * rin[pl];
    size_t ai = (size_t)ch * PIX + p0 + pl;
    if (final_mode) outp[ai] = a_cur[ai] + 2.0f * val;
    else            a_cur[ai] += val;
  }
}

// ===================== launch =====================
extern "C" void kernel_launch(void* const* d_in, const int* in_sizes, int n_in,
                              void* d_out, int out_size, void* d_ws, size_t ws_size,
                              hipStream_t stream) {
  const float* list_a = (const float*)d_in[0];
  const float* list_b = (const float*)d_in[1];
  const float* rots   = (const float*)d_in[3];
  const float* fxs    = (const float*)d_in[5];
  const float* cxs    = (const float*)d_in[6];
  const float* pos_a  = (const float*)d_in[7];
  const float* pos_b  = (const float*)d_in[8];
  const float* Wq     = (const float*)d_in[9];
  const float* bq     = (const float*)d_in[10];
  const float* Wk     = (const float*)d_in[11];
  const float* bk     = (const float*)d_in[12];
  const float* Wv     = (const float*)d_in[13];
  const float* bv     = (const float*)d_in[14];
  const float* in_w   = (const float*)d_in[15];
  const float* in_b   = (const float*)d_in[16];
  const float* out_w  = (const float*)d_in[17];
  const float* out_b  = (const float*)d_in[18];

  float* ws      = (float*)d_ws;
  float* weff    = ws;                          // 196608
  float* beff    = weff + 196608;               // 768
  float* qpos    = beff + 768;                  // 32768
  float* kpos    = qpos + 32768;                // 16384
  float* vpos    = kpos + 16384;                // 16384
  float* a_cur   = vpos + 16384;                // 4194304
  float* xarr    = a_cur + 4194304;             // 51200
  float* yarr    = xarr + 51200;                // 51200
  int*   idxarr  = (int*)(yarr + 51200);        // 51200
  float* cnt     = (float*)(idxarr + 51200);    // 16384
  int*   cursor  = (int*)(cnt + 16384);         // 16384
  int*   offs    = cursor + 16384;              // 16384
  int*   order   = offs + 16384;                // 51200
  ushort* weffh  = (ushort*)(order + 51200);    // 196608 halfs
  ushort* a_recth = weffh + 196608;             // 13107200 halfs
  ushort* bh     = a_recth + 13107200;          // 6553600 halfs
  float* qq      = (float*)(bh + 6553600);      // 13107200 (also attn o in-place)
  float* kkb     = qq + 13107200;               // 6553600
  float* vvb     = kkb + 6553600;               // 6553600
  float* osum    = vvb;                         // alias: vvb dead after attn
  float* enhpre  = kkb;                         // alias: kkb dead after attn

  hipMemcpyAsync(a_cur, list_a, (size_t)4194304 * sizeof(float),
                 hipMemcpyDeviceToDevice, stream);

  // effective weights + biases (tiny)
  gemm_ab_kernel<<<dim3(4, 4, 3), 256, 0, stream>>>(in_w, Wq, Wk, Wv, weff);
  beff_kernel<<<3, 256, 0, stream>>>(in_w, in_b, bq, bk, bv, beff);
  f2b_kernel<<<192, 256, 0, stream>>>(weff, weffh);

  // positional bias tables: pos @ Weff^T + beff
  gemmN_kernel<<<dim3(2, 4), 256, 0, stream>>>(pos_a, weff, beff, qpos, 0);
  gemmN_kernel<<<dim3(1, 4), 256, 0, stream>>>(pos_b, weff + 65536, beff + 256, kpos, 0);
  gemmN_kernel<<<dim3(1, 4), 256, 0, stream>>>(pos_b, weff + 131072, beff + 512, vpos, 0);

  for (int jj = 0; jj < 2; ++jj) {
    int j = jj ? 3 : 0;
    hipMemsetAsync(cnt, 0, (size_t)2 * 16384 * sizeof(float), stream);  // cnt + cursor
    coords_kernel<<<200, 256, 0, stream>>>(rots, fxs, cxs, j, xarr, yarr, idxarr, cnt);
    prefix_kernel<<<1, 256, 0, stream>>>(cnt, offs);
    fill_kernel<<<200, 256, 0, stream>>>(idxarr, offs, cursor, order);
    sample_kernel<<<dim3(200, 256), 256, 0, stream>>>(a_cur, xarr, yarr, a_recth);
    const float* bsrc = list_b + (size_t)j * 6553600;
    f2b_kernel<<<6400, 256, 0, stream>>>(bsrc, bh);
    // MFMA projections
    mfma_gemmT_kernel<<<dim3(400, 2), 256, 0, stream>>>(a_recth, MS, weffh, qpos, qq, 128);
    mfma_gemmT_kernel<<<dim3(200, 2), 256, 0, stream>>>(bh, MB, weffh + 65536, kpos, kkb, 64);
    mfma_gemmT_kernel<<<dim3(200, 2), 256, 0, stream>>>(bh, MB, weffh + 131072, vpos, vvb, 64);
    attn_kernel<<<3200, 128, 0, stream>>>(qq, kkb, vvb, qq);   // o in-place into qq
    // per-pixel reduction of o, then single out-proj GEMM on 16384 rows
    gather_kernel<<<16384, 256, 0, stream>>>(qq, order, offs, cnt, osum);
    gemmN_kernel<<<dim3(256, 4), 256, 0, stream>>>(osum, out_w, nullptr, enhpre, 2);
    update_kernel<<<1024, 256, 0, stream>>>(a_cur, enhpre, cnt, out_b,
                                            jj ? (float*)d_out : nullptr, jj);
  }
}

// Round 4
// 1029.389 us; speedup vs baseline: 2.4851x; 1.1308x over previous
//
#include <hip/hip_runtime.h>

// Problem constants
// a: (256,128,128)  b: (4,256,64,400)  E=256 NH=8 DH=32  B=400 Lq=128 Lk=64
#define PIX 16384          // 128*128
#define MS 51200           // H1*W2 samples
#define MB 25600           // H2*W2

typedef __attribute__((ext_vector_type(8))) short short8;
typedef __attribute__((ext_vector_type(4))) float floatx4;

__device__ inline ushort f2b(float x) {
  uint u = __float_as_uint(x);
  return (ushort)((u + 0x7fffu + ((u >> 16) & 1u)) >> 16);
}
__device__ inline float b2f(ushort u) {
  return __uint_as_float(((uint)u) << 16);
}

// ===================== coords: x,y, scatter idx, counts =====================
__global__ __launch_bounds__(256) void coords_kernel(
    const float* __restrict__ rots, const float* __restrict__ fxs,
    const float* __restrict__ cxs, int j,
    float* __restrict__ xarr, float* __restrict__ yarr,
    int* __restrict__ idxarr, float* __restrict__ cnt)
{
  int s = blockIdx.x * 256 + threadIdx.x;      // 0..51199, s = h*400 + w
  int h = s / 400;
  int w = s - h * 400;
  float fx = fxs[j], cx = cxs[j];
  const float* R = rots + j * 9;
  float cr = R[3];        // rots[1][0]
  float sr = -R[0];       // -rots[0][0]
  float t = (2.0f * (float)w + 1.0f - cx) / fx;      // tan(ang)
  float inv = 1.0f / sqrtf(1.0f + t * t);            // cos(ang)
  float ca = (cr + sr * t) * inv;                    // cr*cos + sr*sin
  float sa = (cr * t - sr) * inv;                    // -sr*cos + cr*sin
  float rad = ((float)h * (1.0f / 127.0f)) * 90.50966799187808f;
  float x = 64.0f + rad * ca;
  float y = 64.0f - rad * sa;
  xarr[s] = x;
  yarr[s] = y;
  int xi = (int)fminf(fmaxf(rintf(x), 0.0f), 127.0f);
  int yi = (int)fminf(fmaxf(rintf(y), 0.0f), 127.0f);
  int pix = yi * 128 + xi;
  idxarr[s] = pix;
  atomicAdd(&cnt[pix], 1.0f);
}

// ===================== prefix scan over pixel counts =====================
__global__ __launch_bounds__(256) void prefix_kernel(
    const float* __restrict__ cnt, int* __restrict__ offsets)
{
  __shared__ int sh[256];
  int t = threadIdx.x;
  int base = t * 64;
  int sum = 0;
  for (int i = 0; i < 64; ++i) sum += (int)cnt[base + i];
  sh[t] = sum;
  __syncthreads();
  for (int d = 1; d < 256; d <<= 1) {
    int v = (t >= d) ? sh[t - d] : 0;
    __syncthreads();
    sh[t] += v;
    __syncthreads();
  }
  int run = sh[t] - sum;   // exclusive prefix for this thread's chunk
  for (int i = 0; i < 64; ++i) {
    offsets[base + i] = run;
    run += (int)cnt[base + i];
  }
}

// ===================== fill sorted sample lists =====================
__global__ __launch_bounds__(256) void fill_kernel(
    const int* __restrict__ idxarr, const int* __restrict__ offsets,
    int* __restrict__ cursor, int* __restrict__ order)
{
  int s = blockIdx.x * 256 + threadIdx.x;
  int pix = idxarr[s];
  int pos = offsets[pix] + atomicAdd(&cursor[pix], 1);
  // store the attention-output row index m = w*128 + h  (s = h*400 + w)
  order[pos] = (s % 400) * 128 + (s / 400);
}

// ===================== bilinear sampler: a_recth[c][s] (bf16) ==============
__global__ __launch_bounds__(256) void sample_kernel(
    const float* __restrict__ a_cur, const float* __restrict__ xarr,
    const float* __restrict__ yarr, ushort* __restrict__ a_recth)
{
  int s = blockIdx.x * 256 + threadIdx.x;   // sample index
  int c = blockIdx.y;                       // channel
  float x = fminf(fmaxf(xarr[s], 0.0f), 127.0f);
  float y = fminf(fmaxf(yarr[s], 0.0f), 127.0f);
  float x0f = floorf(x), y0f = floorf(y);
  int x0 = (int)x0f, y0 = (int)y0f;
  int x1 = min(x0 + 1, 127), y1 = min(y0 + 1, 127);
  float wx = x - x0f, wy = y - y0f;
  const float* img = a_cur + (size_t)c * PIX;
  float v00 = img[y0 * 128 + x0];
  float v01 = img[y0 * 128 + x1];
  float v10 = img[y1 * 128 + x0];
  float v11 = img[y1 * 128 + x1];
  float val = v00 * (1.0f - wx) * (1.0f - wy) + v01 * wx * (1.0f - wy)
            + v10 * (1.0f - wx) * wy + v11 * wx * wy;
  a_recth[(size_t)c * MS + s] = f2b(val);
}

// ===================== f32 -> bf16 bulk convert (float4-wide) ==============
__global__ __launch_bounds__(256) void f2b_kernel(
    const float* __restrict__ in, ushort* __restrict__ out)
{
  int t = blockIdx.x * 256 + threadIdx.x;
  float4 v = ((const float4*)in)[t];
  ushort4 o;
  o.x = f2b(v.x); o.y = f2b(v.y); o.z = f2b(v.z); o.w = f2b(v.w);
  ((ushort4*)out)[t] = o;
}

// ===================== MFMA GEMM: C = A^T(K-major bf16) @ W^T(bf16) ========
// Ah[k][m] stride Astride; Wh[f][k]; bias fp32 [h][256];
// out row permute: m = h*400+w -> row = w*Hdim+h;  Couth[row*256+f] bf16
#define BKP 144   // LDS A row stride in halfs (k-row -> 128 m + swizzle pad)
#define WKP 40    // LDS W row stride in halfs (32 k + pad)
__global__ __launch_bounds__(256) void mfma_gemmT_kernel(
    const ushort* __restrict__ Ah, int Astride,
    const ushort* __restrict__ Wh, const float* __restrict__ bias,
    ushort* __restrict__ Couth, int Hdim)
{
  __shared__ ushort lA[32 * BKP];   // [k_local][m' (xor-swizzled)]
  __shared__ ushort lW[128 * WKP];  // [f_local][k_local]
  int m0 = blockIdx.x * 128;
  int n0 = blockIdx.y * 128;
  int tid = threadIdx.x;
  int lane = tid & 63;
  int wave = tid >> 6;
  int col = lane & 15;
  int quad = lane >> 4;
  int sw = (wave & 1) * 64;     // wave sample-offset in tile
  int fw = (wave >> 1) * 64;    // wave feature-offset in tile
  floatx4 acc[4][4];
#pragma unroll
  for (int i = 0; i < 4; ++i)
#pragma unroll
    for (int jx = 0; jx < 4; ++jx) acc[i][jx] = (floatx4){0.f, 0.f, 0.f, 0.f};

  for (int kb = 0; kb < 256; kb += 32) {
#pragma unroll
    for (int half = 0; half < 2; ++half) {
      int L = tid + half * 256;
      int r = L >> 4;            // k row 0..31
      int c = L & 15;            // 16-byte m chunk
      uint4 v = *(const uint4*)(Ah + (size_t)(kb + r) * Astride + m0 + c * 8);
      int mp = (c * 8) ^ ((r >> 3) * 16);
      *(uint4*)&lA[r * BKP + mp] = v;
    }
#pragma unroll
    for (int half = 0; half < 2; ++half) {
      int L = tid + half * 256;
      int f = L >> 2;            // 0..127
      int seg = L & 3;           // 8-half chunk of k
      uint4 v = *(const uint4*)(Wh + (size_t)(n0 + f) * 256 + kb + seg * 8);
      *(uint4*)&lW[f * WKP + seg * 8] = v;
    }
    __syncthreads();
    short8 aop[4];
#pragma unroll
    for (int tf = 0; tf < 4; ++tf) {
      int fr = fw + tf * 16 + col;
      aop[tf] = *(const short8*)&lW[fr * WKP + quad * 8];
    }
#pragma unroll
    for (int ts = 0; ts < 4; ++ts) {
      int mi = sw + ts * 16 + col;
      int mp = mi ^ (quad * 16);
      short8 bop;
#pragma unroll
      for (int jx = 0; jx < 8; ++jx)
        bop[jx] = (short)lA[(quad * 8 + jx) * BKP + mp];
#pragma unroll
      for (int tf = 0; tf < 4; ++tf)
        acc[ts][tf] = __builtin_amdgcn_mfma_f32_16x16x32_bf16(
            aop[tf], bop, acc[ts][tf], 0, 0, 0);
    }
    __syncthreads();
  }
  // epilogue: D col=lane&15 -> sample, row=quad*4+reg -> feature; bf16 out
#pragma unroll
  for (int ts = 0; ts < 4; ++ts) {
    int m = m0 + sw + ts * 16 + col;
    int h = m / 400;
    int w = m - h * 400;
    size_t obase = (size_t)(w * Hdim + h) * 256;
#pragma unroll
    for (int tf = 0; tf < 4; ++tf) {
      int f = n0 + fw + tf * 16 + quad * 4;
      float4 bv = *(const float4*)(bias + h * 256 + f);
      ushort4 ov;
      ov.x = f2b(acc[ts][tf][0] + bv.x);
      ov.y = f2b(acc[ts][tf][1] + bv.y);
      ov.z = f2b(acc[ts][tf][2] + bv.z);
      ov.w = f2b(acc[ts][tf][3] + bv.w);
      *(ushort4*)(Couth + obase + f) = ov;
    }
  }
}

// ===================== MFMA flash attention =====================
// grid (400, 2), 256 threads = 4 waves; wave handles head = blockIdx.y*4+wave.
// Q/K/V bf16 [m][256]; O bf16 [m][256].
#define KP 40   // K LDS row pitch (halfs)
#define VP 72   // V^T LDS row pitch (halfs)
#define PP 72   // P LDS row pitch (halfs)
__global__ __launch_bounds__(256) void attn_mfma_kernel(
    const ushort* __restrict__ qh, const ushort* __restrict__ kh,
    const ushort* __restrict__ vh, ushort* __restrict__ obuf)
{
  __shared__ ushort lK[4][64 * KP];
  __shared__ ushort lV[4][32 * VP];
  __shared__ ushort lP[4][16 * PP];
  int b = blockIdx.x;
  int wave = threadIdx.x >> 6;
  int lane = threadIdx.x & 63;
  int head = blockIdx.y * 4 + wave;
  int col = lane & 15, quad = lane >> 4;
  ushort* Kw = lK[wave];
  ushort* Vw = lV[wave];
  ushort* Pw = lP[wave];

  // stage K rows (lane = key) and V transposed
  {
    const ushort* ksrc = kh + ((size_t)(b * 64 + lane)) * 256 + head * 32;
    uint4 k0 = *(const uint4*)(ksrc);
    uint4 k1 = *(const uint4*)(ksrc + 8);
    uint4 k2 = *(const uint4*)(ksrc + 16);
    uint4 k3 = *(const uint4*)(ksrc + 24);
    ushort* kd = Kw + lane * KP;
    *(uint4*)(kd) = k0; *(uint4*)(kd + 8) = k1;
    *(uint4*)(kd + 16) = k2; *(uint4*)(kd + 24) = k3;
    const ushort* vsrc = vh + ((size_t)(b * 64 + lane)) * 256 + head * 32;
    ushort vr[32];
    *(uint4*)(vr) = *(const uint4*)(vsrc);
    *(uint4*)(vr + 8) = *(const uint4*)(vsrc + 8);
    *(uint4*)(vr + 16) = *(const uint4*)(vsrc + 16);
    *(uint4*)(vr + 24) = *(const uint4*)(vsrc + 24);
#pragma unroll
    for (int d = 0; d < 32; ++d) Vw[d * VP + lane] = vr[d];
  }
  __syncthreads();

  const float scl = 0.17677669529663687f;   // 1/sqrt(32)
  for (int qt = 0; qt < 8; ++qt) {
    // Q A-frag straight from global: A[m=col][k=quad*8+j]
    short8 aq = *(const short8*)(qh +
        ((size_t)(b * 128 + qt * 16 + col)) * 256 + head * 32 + quad * 8);
    // QK^T: 4 k-tiles; B frag = K[key=t*16+col][d=quad*8+j]
    floatx4 s0 = {0.f,0.f,0.f,0.f}, s1 = s0, s2 = s0, s3 = s0;
    {
      short8 b0 = *(const short8*)(Kw + (0 * 16 + col) * KP + quad * 8);
      short8 b1 = *(const short8*)(Kw + (1 * 16 + col) * KP + quad * 8);
      short8 b2 = *(const short8*)(Kw + (2 * 16 + col) * KP + quad * 8);
      short8 b3 = *(const short8*)(Kw + (3 * 16 + col) * KP + quad * 8);
      s0 = __builtin_amdgcn_mfma_f32_16x16x32_bf16(aq, b0, s0, 0, 0, 0);
      s1 = __builtin_amdgcn_mfma_f32_16x16x32_bf16(aq, b1, s1, 0, 0, 0);
      s2 = __builtin_amdgcn_mfma_f32_16x16x32_bf16(aq, b2, s2, 0, 0, 0);
      s3 = __builtin_amdgcn_mfma_f32_16x16x32_bf16(aq, b3, s3, 0, 0, 0);
    }
    // softmax in C-layout: row = quad*4+r, col = col+16t
    float e[4][4], mr[4], sm[4];
#pragma unroll
    for (int r = 0; r < 4; ++r) {
      float v0 = s0[r] * scl, v1 = s1[r] * scl;
      float v2 = s2[r] * scl, v3 = s3[r] * scl;
      e[0][r] = v0; e[1][r] = v1; e[2][r] = v2; e[3][r] = v3;
      mr[r] = fmaxf(fmaxf(v0, v1), fmaxf(v2, v3));
    }
#pragma unroll
    for (int mask = 1; mask <= 8; mask <<= 1)
#pragma unroll
      for (int r = 0; r < 4; ++r)
        mr[r] = fmaxf(mr[r], __shfl_xor(mr[r], mask, 64));
#pragma unroll
    for (int r = 0; r < 4; ++r) {
      float acc = 0.f;
#pragma unroll
      for (int t = 0; t < 4; ++t) {
        float ev = __expf(e[t][r] - mr[r]);
        e[t][r] = ev;
        acc += ev;
      }
      sm[r] = acc;
    }
#pragma unroll
    for (int mask = 1; mask <= 8; mask <<= 1)
#pragma unroll
      for (int r = 0; r < 4; ++r)
        sm[r] += __shfl_xor(sm[r], mask, 64);
    // P -> LDS (bf16), row-major [q][key]
#pragma unroll
    for (int t = 0; t < 4; ++t)
#pragma unroll
      for (int r = 0; r < 4; ++r)
        Pw[(quad * 4 + r) * PP + t * 16 + col] = f2b(e[t][r]);
    __syncthreads();
    // PV: A = P[q=col][key=c*32+quad*8+j]; B = V^T[d][key]
    floatx4 o0 = {0.f,0.f,0.f,0.f}, o1 = o0;
#pragma unroll
    for (int c = 0; c < 2; ++c) {
      short8 ap = *(const short8*)(Pw + col * PP + c * 32 + quad * 8);
      short8 v0 = *(const short8*)(Vw + col * VP + c * 32 + quad * 8);
      short8 v1 = *(const short8*)(Vw + (16 + col) * VP + c * 32 + quad * 8);
      o0 = __builtin_amdgcn_mfma_f32_16x16x32_bf16(ap, v0, o0, 0, 0, 0);
      o1 = __builtin_amdgcn_mfma_f32_16x16x32_bf16(ap, v1, o1, 0, 0, 0);
    }
    // normalize (sm rows == O rows: quad*4+r) and store bf16
#pragma unroll
    for (int r = 0; r < 4; ++r) {
      float iv = 1.0f / sm[r];
      size_t row = (size_t)(b * 128 + qt * 16 + quad * 4 + r) * 256 + head * 32;
      obuf[row + col] = f2b(o0[r] * iv);
      obuf[row + 16 + col] = f2b(o1[r] * iv);
    }
    __syncthreads();   // Pw reused next iteration
  }
}

// ===================== GEMM (A M-major fp32): C = A * W^T ==================
// mode 0: Cout[m*256+f] = acc + biasf[f];  mode 2: Cout[m*256+f] = acc
__global__ __launch_bounds__(256) void gemmN_kernel(
    const float* __restrict__ A, const float* __restrict__ Wt,
    const float* __restrict__ biasf, float* __restrict__ Cout, int mode)
{
  __shared__ float As[64][17];
  __shared__ float Ws[16][65];
  int m0 = blockIdx.x * 64;
  int n0 = blockIdx.y * 64;
  int tid = threadIdx.x;
  int tx = tid & 15, ty = tid >> 4;
  float acc[4][4] = {};
  for (int k0 = 0; k0 < 256; k0 += 16) {
    {
      int m = tid >> 2;            // 0..63
      int kq = (tid & 3) << 2;
      float4 v = *(const float4*)(A + (size_t)(m0 + m) * 256 + k0 + kq);
      As[m][kq + 0] = v.x; As[m][kq + 1] = v.y;
      As[m][kq + 2] = v.z; As[m][kq + 3] = v.w;
    }
    {
      int f = tid >> 2;
      int kq = (tid & 3) << 2;
      float4 v = *(const float4*)(Wt + (size_t)(n0 + f) * 256 + k0 + kq);
      Ws[kq + 0][f] = v.x; Ws[kq + 1][f] = v.y;
      Ws[kq + 2][f] = v.z; Ws[kq + 3][f] = v.w;
    }
    __syncthreads();
#pragma unroll
    for (int kk = 0; kk < 16; ++kk) {
      float a[4], b[4];
#pragma unroll
      for (int i = 0; i < 4; ++i) a[i] = As[ty * 4 + i][kk];
#pragma unroll
      for (int jj = 0; jj < 4; ++jj) b[jj] = Ws[kk][tx * 4 + jj];
#pragma unroll
      for (int i = 0; i < 4; ++i)
#pragma unroll
        for (int jj = 0; jj < 4; ++jj) acc[i][jj] += a[i] * b[jj];
    }
    __syncthreads();
  }
#pragma unroll
  for (int i = 0; i < 4; ++i) {
    int m = m0 + ty * 4 + i;
    int f = n0 + tx * 4;
    float4 ov;
    if (mode == 0) {
      float4 bv = *(const float4*)(biasf + f);
      ov.x = acc[i][0] + bv.x; ov.y = acc[i][1] + bv.y;
      ov.z = acc[i][2] + bv.z; ov.w = acc[i][3] + bv.w;
    } else {
      ov.x = acc[i][0]; ov.y = acc[i][1];
      ov.z = acc[i][2]; ov.w = acc[i][3];
    }
    *(float4*)(Cout + (size_t)m * 256 + f) = ov;
  }
}

// ===================== GEMM A[m][k] * B[k][n] (effective weights) ==========
__global__ __launch_bounds__(256) void gemm_ab_kernel(
    const float* __restrict__ in_w, const float* __restrict__ Wq,
    const float* __restrict__ Wk, const float* __restrict__ Wv,
    float* __restrict__ weff)
{
  int z = blockIdx.z;
  const float* A = in_w + (size_t)z * 65536;
  const float* B = (z == 0) ? Wq : ((z == 1) ? Wk : Wv);
  float* C = weff + (size_t)z * 65536;
  __shared__ float As[64][17];
  __shared__ float Bs[16][64];
  int m0 = blockIdx.x * 64;
  int n0 = blockIdx.y * 64;
  int tid = threadIdx.x;
  int tx = tid & 15, ty = tid >> 4;
  float acc[4][4] = {};
  for (int k0 = 0; k0 < 256; k0 += 16) {
    {
      int m = tid >> 2;
      int kq = (tid & 3) << 2;
      float4 v = *(const float4*)(A + (size_t)(m0 + m) * 256 + k0 + kq);
      As[m][kq + 0] = v.x; As[m][kq + 1] = v.y;
      As[m][kq + 2] = v.z; As[m][kq + 3] = v.w;
    }
    {
      int k = tid >> 4;
      int nq = (tid & 15) << 2;
      float4 v = *(const float4*)(B + (size_t)(k0 + k) * 256 + n0 + nq);
      *(float4*)(&Bs[k][nq]) = v;
    }
    __syncthreads();
#pragma unroll
    for (int kk = 0; kk < 16; ++kk) {
      float a[4], b[4];
#pragma unroll
      for (int i = 0; i < 4; ++i) a[i] = As[ty * 4 + i][kk];
#pragma unroll
      for (int jj = 0; jj < 4; ++jj) b[jj] = Bs[kk][tx * 4 + jj];
#pragma unroll
      for (int i = 0; i < 4; ++i)
#pragma unroll
        for (int jj = 0; jj < 4; ++jj) acc[i][jj] += a[i] * b[jj];
    }
    __syncthreads();
  }
#pragma unroll
  for (int i = 0; i < 4; ++i) {
    int m = m0 + ty * 4 + i;
    *(float4*)(C + (size_t)m * 256 + n0 + tx * 4) = *(float4*)&acc[i][0];
  }
}

// ===================== effective biases =====================
__global__ void beff_kernel(const float* __restrict__ in_w, const float* __restrict__ in_b,
                            const float* __restrict__ bq, const float* __restrict__ bk,
                            const float* __restrict__ bv, float* __restrict__ beff)
{
  int z = blockIdx.x;
  int f = threadIdx.x;
  const float* bsrc = (z == 0) ? bq : ((z == 1) ? bk : bv);
  const float* row = in_w + (size_t)(z * 256 + f) * 256;
  float acc = in_b[z * 256 + f];
  for (int e = 0; e < 256; ++e) acc += row[e] * bsrc[e];
  beff[z * 256 + f] = acc;
}

// ===================== per-pixel gather-reduce of attention outputs ========
// osum[p][c] = sum over samples mapping to pixel p of obuf[m][c]  (bf16 in)
__global__ __launch_bounds__(256) void gather_kernel(
    const ushort* __restrict__ obuf, const int* __restrict__ order,
    const int* __restrict__ offsets, const float* __restrict__ cnt,
    float* __restrict__ osum)
{
  int p = blockIdx.x;
  int c = threadIdx.x;
  int off = offsets[p];
  int n = (int)cnt[p];
  float acc = 0.0f, acc2 = 0.0f;
  int i = 0;
  for (; i + 2 <= n; i += 2) {
    int m0 = order[off + i], m1 = order[off + i + 1];
    acc  += b2f(obuf[(size_t)m0 * 256 + c]);
    acc2 += b2f(obuf[(size_t)m1 * 256 + c]);
  }
  if (i < n) acc += b2f(obuf[(size_t)order[off + i] * 256 + c]);
  osum[(size_t)p * 256 + c] = acc + acc2;
}

// ===================== residual update / final (with LDS transpose) ========
__global__ __launch_bounds__(256) void update_kernel(
    float* __restrict__ a_cur, const float* __restrict__ enhpre,
    const float* __restrict__ cnt, const float* __restrict__ out_b,
    float* __restrict__ outp, int final_mode)
{
  __shared__ float tile[16][260];
  __shared__ float obs[256];
  __shared__ float cn[16];
  __shared__ float rin[16];
  int p0 = blockIdx.x * 16;
  int t = threadIdx.x;
  obs[t] = out_b[t];
  if (t < 16) {
    float c = cnt[p0 + t];
    cn[t] = c;
    rin[t] = 1.0f / fmaxf(c, 1.0f);
  }
#pragma unroll
  for (int q = 0; q < 4; ++q) {
    int l = q * 256 + t;
    int row = l >> 6;
    int colq = (l & 63) << 2;
    float4 v = *(const float4*)(enhpre + (size_t)(p0 + row) * 256 + colq);
    tile[row][colq] = v.x; tile[row][colq + 1] = v.y;
    tile[row][colq + 2] = v.z; tile[row][colq + 3] = v.w;
  }
  __syncthreads();
  int pl = t & 15;
  int c0 = t >> 4;
#pragma unroll
  for (int cc = 0; cc < 16; ++cc) {
    int ch = cc * 16 + c0;
    float val = (tile[pl][ch] + cn[pl] * obs[ch]) * rin[pl];
    size_t ai = (size_t)ch * PIX + p0 + pl;
    if (final_mode) outp[ai] = a_cur[ai] + 2.0f * val;
    else            a_cur[ai] += val;
  }
}

// ===================== launch =====================
extern "C" void kernel_launch(void* const* d_in, const int* in_sizes, int n_in,
                              void* d_out, int out_size, void* d_ws, size_t ws_size,
                              hipStream_t stream) {
  const float* list_a = (const float*)d_in[0];
  const float* list_b = (const float*)d_in[1];
  const float* rots   = (const float*)d_in[3];
  const float* fxs    = (const float*)d_in[5];
  const float* cxs    = (const float*)d_in[6];
  const float* pos_a  = (const float*)d_in[7];
  const float* pos_b  = (const float*)d_in[8];
  const float* Wq     = (const float*)d_in[9];
  const float* bq     = (const float*)d_in[10];
  const float* Wk     = (const float*)d_in[11];
  const float* bk     = (const float*)d_in[12];
  const float* Wv     = (const float*)d_in[13];
  const float* bv     = (const float*)d_in[14];
  const float* in_w   = (const float*)d_in[15];
  const float* in_b   = (const float*)d_in[16];
  const float* out_w  = (const float*)d_in[17];
  const float* out_b  = (const float*)d_in[18];

  float* ws      = (float*)d_ws;
  float* weff    = ws;                          // 196608 f
  float* beff    = weff + 196608;               // 768 f
  float* qpos    = beff + 768;                  // 32768 f
  float* kpos    = qpos + 32768;                // 16384 f
  float* vpos    = kpos + 16384;                // 16384 f
  float* a_cur   = vpos + 16384;                // 4194304 f
  float* xarr    = a_cur + 4194304;             // 51200 f
  float* yarr    = xarr + 51200;                // 51200 f
  int*   idxarr  = (int*)(yarr + 51200);        // 51200
  float* cnt     = (float*)(idxarr + 51200);    // 16384 f
  int*   cursor  = (int*)(cnt + 16384);         // 16384
  int*   offs    = cursor + 16384;              // 16384
  int*   order   = offs + 16384;                // 51200
  ushort* weffh  = (ushort*)(order + 51200);    // 196608 h
  ushort* a_recth = weffh + 196608;             // 13107200 h (also obuf alias)
  ushort* bh     = a_recth + 13107200;          // 6553600 h
  ushort* qh     = bh + 6553600;                // 13107200 h (osum alias)
  ushort* kh     = qh + 13107200;               // 6553600 h  (enhpre alias ->)
  ushort* vh     = kh + 6553600;                // 6553600 h
  ushort* obufh  = a_recth;                     // alias: a_recth dead after Q-proj
  float* osum    = (float*)qh;                  // alias: qh dead after attn
  float* enhpre  = (float*)kh;                  // alias: kh/vh dead after attn

  hipMemcpyAsync(a_cur, list_a, (size_t)4194304 * sizeof(float),
                 hipMemcpyDeviceToDevice, stream);

  // effective weights + biases (tiny)
  gemm_ab_kernel<<<dim3(4, 4, 3), 256, 0, stream>>>(in_w, Wq, Wk, Wv, weff);
  beff_kernel<<<3, 256, 0, stream>>>(in_w, in_b, bq, bk, bv, beff);
  f2b_kernel<<<192, 256, 0, stream>>>(weff, weffh);

  // positional bias tables: pos @ Weff^T + beff
  gemmN_kernel<<<dim3(2, 4), 256, 0, stream>>>(pos_a, weff, beff, qpos, 0);
  gemmN_kernel<<<dim3(1, 4), 256, 0, stream>>>(pos_b, weff + 65536, beff + 256, kpos, 0);
  gemmN_kernel<<<dim3(1, 4), 256, 0, stream>>>(pos_b, weff + 131072, beff + 512, vpos, 0);

  for (int jj = 0; jj < 2; ++jj) {
    int j = jj ? 3 : 0;
    hipMemsetAsync(cnt, 0, (size_t)2 * 16384 * sizeof(float), stream);  // cnt + cursor
    coords_kernel<<<200, 256, 0, stream>>>(rots, fxs, cxs, j, xarr, yarr, idxarr, cnt);
    prefix_kernel<<<1, 256, 0, stream>>>(cnt, offs);
    fill_kernel<<<200, 256, 0, stream>>>(idxarr, offs, cursor, order);
    sample_kernel<<<dim3(200, 256), 256, 0, stream>>>(a_cur, xarr, yarr, a_recth);
    const float* bsrc = list_b + (size_t)j * 6553600;
    f2b_kernel<<<6400, 256, 0, stream>>>(bsrc, bh);
    // MFMA projections (bf16 out)
    mfma_gemmT_kernel<<<dim3(400, 2), 256, 0, stream>>>(a_recth, MS, weffh, qpos, qh, 128);
    mfma_gemmT_kernel<<<dim3(200, 2), 256, 0, stream>>>(bh, MB, weffh + 65536, kpos, kh, 64);
    mfma_gemmT_kernel<<<dim3(200, 2), 256, 0, stream>>>(bh, MB, weffh + 131072, vpos, vh, 64);
    // MFMA flash attention (O bf16 into obufh = a_recth region)
    attn_mfma_kernel<<<dim3(400, 2), 256, 0, stream>>>(qh, kh, vh, obufh);
    // per-pixel reduction of O, then single out-proj GEMM on 16384 rows
    gather_kernel<<<16384, 256, 0, stream>>>(obufh, order, offs, cnt, osum);
    gemmN_kernel<<<dim3(256, 4), 256, 0, stream>>>(osum, out_w, nullptr, enhpre, 2);
    update_kernel<<<1024, 256, 0, stream>>>(a_cur, enhpre, cnt, out_b,
                                            jj ? (float*)d_out : nullptr, jj);
  }
}

// Round 5
// 944.788 us; speedup vs baseline: 2.7076x; 1.0895x over previous
//
#include <hip/hip_runtime.h>

// Problem constants
// a: (256,128,128)  b: (4,256,64,400)  E=256 NH=8 DH=32  B=400 Lq=128 Lk=64
#define PIX 16384          // 128*128
#define MS 51200           // H1*W2 samples
#define MB 25600           // H2*W2

typedef __attribute__((ext_vector_type(8))) short short8;
typedef __attribute__((ext_vector_type(4))) float floatx4;

__device__ inline ushort f2b(float x) {
  uint u = __float_as_uint(x);
  return (ushort)((u + 0x7fffu + ((u >> 16) & 1u)) >> 16);
}
__device__ inline float b2f(ushort u) {
  return __uint_as_float(((uint)u) << 16);
}

// ===================== coords: x,y, scatter idx, counts =====================
__global__ __launch_bounds__(256) void coords_kernel(
    const float* __restrict__ rots, const float* __restrict__ fxs,
    const float* __restrict__ cxs, int j,
    float* __restrict__ xarr, float* __restrict__ yarr,
    int* __restrict__ idxarr, float* __restrict__ cnt)
{
  int s = blockIdx.x * 256 + threadIdx.x;      // 0..51199, s = h*400 + w
  int h = s / 400;
  int w = s - h * 400;
  float fx = fxs[j], cx = cxs[j];
  const float* R = rots + j * 9;
  float cr = R[3];        // rots[1][0]
  float sr = -R[0];       // -rots[0][0]
  float t = (2.0f * (float)w + 1.0f - cx) / fx;      // tan(ang)
  float inv = 1.0f / sqrtf(1.0f + t * t);            // cos(ang)
  float ca = (cr + sr * t) * inv;                    // cr*cos + sr*sin
  float sa = (cr * t - sr) * inv;                    // -sr*cos + cr*sin
  float rad = ((float)h * (1.0f / 127.0f)) * 90.50966799187808f;
  float x = 64.0f + rad * ca;
  float y = 64.0f - rad * sa;
  xarr[s] = x;
  yarr[s] = y;
  int xi = (int)fminf(fmaxf(rintf(x), 0.0f), 127.0f);
  int yi = (int)fminf(fmaxf(rintf(y), 0.0f), 127.0f);
  int pix = yi * 128 + xi;
  idxarr[s] = pix;
  atomicAdd(&cnt[pix], 1.0f);
}

// ===================== prefix scan over pixel counts =====================
__global__ __launch_bounds__(256) void prefix_kernel(
    const float* __restrict__ cnt, int* __restrict__ offsets)
{
  __shared__ int sh[256];
  int t = threadIdx.x;
  int base = t * 64;
  int sum = 0;
  for (int i = 0; i < 64; ++i) sum += (int)cnt[base + i];
  sh[t] = sum;
  __syncthreads();
  for (int d = 1; d < 256; d <<= 1) {
    int v = (t >= d) ? sh[t - d] : 0;
    __syncthreads();
    sh[t] += v;
    __syncthreads();
  }
  int run = sh[t] - sum;   // exclusive prefix for this thread's chunk
  for (int i = 0; i < 64; ++i) {
    offsets[base + i] = run;
    run += (int)cnt[base + i];
  }
}

// ===================== fill sorted sample lists =====================
__global__ __launch_bounds__(256) void fill_kernel(
    const int* __restrict__ idxarr, const int* __restrict__ offsets,
    int* __restrict__ cursor, int* __restrict__ order)
{
  int s = blockIdx.x * 256 + threadIdx.x;
  int pix = idxarr[s];
  int pos = offsets[pix] + atomicAdd(&cursor[pix], 1);
  // store the attention-output row index m = w*128 + h  (s = h*400 + w)
  order[pos] = (s % 400) * 128 + (s / 400);
}

// ===================== bilinear sampler: a_recth[c][s] (bf16) ==============
__global__ __launch_bounds__(256) void sample_kernel(
    const float* __restrict__ a_cur, const float* __restrict__ xarr,
    const float* __restrict__ yarr, ushort* __restrict__ a_recth)
{
  int s = blockIdx.x * 256 + threadIdx.x;   // sample index
  int c = blockIdx.y;                       // channel
  float x = fminf(fmaxf(xarr[s], 0.0f), 127.0f);
  float y = fminf(fmaxf(yarr[s], 0.0f), 127.0f);
  float x0f = floorf(x), y0f = floorf(y);
  int x0 = (int)x0f, y0 = (int)y0f;
  int x1 = min(x0 + 1, 127), y1 = min(y0 + 1, 127);
  float wx = x - x0f, wy = y - y0f;
  const float* img = a_cur + (size_t)c * PIX;
  float v00 = img[y0 * 128 + x0];
  float v01 = img[y0 * 128 + x1];
  float v10 = img[y1 * 128 + x0];
  float v11 = img[y1 * 128 + x1];
  float val = v00 * (1.0f - wx) * (1.0f - wy) + v01 * wx * (1.0f - wy)
            + v10 * (1.0f - wx) * wy + v11 * wx * wy;
  a_recth[(size_t)c * MS + s] = f2b(val);
}

// ===================== f32 -> bf16 bulk convert (float4-wide) ==============
__global__ __launch_bounds__(256) void f2b_kernel(
    const float* __restrict__ in, ushort* __restrict__ out)
{
  int t = blockIdx.x * 256 + threadIdx.x;
  float4 v = ((const float4*)in)[t];
  ushort4 o;
  o.x = f2b(v.x); o.y = f2b(v.y); o.z = f2b(v.z); o.w = f2b(v.w);
  ((ushort4*)out)[t] = o;
}

// ===================== MFMA GEMM: C = A^T(K-major bf16) @ W^T(bf16) ========
// Ah[k][m] stride Astride; Wh[f][k]; bias fp32 [h][256];
// out row permute: m = h*400+w -> row = w*Hdim+h;  Couth[row*256+f] bf16
#define BKP 144   // LDS A row stride in halfs (k-row -> 128 m + swizzle pad)
#define WKP 40    // LDS W row stride in halfs (32 k + pad)
__global__ __launch_bounds__(256) void mfma_gemmT_kernel(
    const ushort* __restrict__ Ah, int Astride,
    const ushort* __restrict__ Wh, const float* __restrict__ bias,
    ushort* __restrict__ Couth, int Hdim)
{
  __shared__ ushort lA[32 * BKP];   // [k_local][m' (xor-swizzled)]
  __shared__ ushort lW[128 * WKP];  // [f_local][k_local]
  int m0 = blockIdx.x * 128;
  int n0 = blockIdx.y * 128;
  int tid = threadIdx.x;
  int lane = tid & 63;
  int wave = tid >> 6;
  int col = lane & 15;
  int quad = lane >> 4;
  int sw = (wave & 1) * 64;     // wave sample-offset in tile
  int fw = (wave >> 1) * 64;    // wave feature-offset in tile
  floatx4 acc[4][4];
#pragma unroll
  for (int i = 0; i < 4; ++i)
#pragma unroll
    for (int jx = 0; jx < 4; ++jx) acc[i][jx] = (floatx4){0.f, 0.f, 0.f, 0.f};

  for (int kb = 0; kb < 256; kb += 32) {
#pragma unroll
    for (int half = 0; half < 2; ++half) {
      int L = tid + half * 256;
      int r = L >> 4;            // k row 0..31
      int c = L & 15;            // 16-byte m chunk
      uint4 v = *(const uint4*)(Ah + (size_t)(kb + r) * Astride + m0 + c * 8);
      int mp = (c * 8) ^ ((r >> 3) * 16);
      *(uint4*)&lA[r * BKP + mp] = v;
    }
#pragma unroll
    for (int half = 0; half < 2; ++half) {
      int L = tid + half * 256;
      int f = L >> 2;            // 0..127
      int seg = L & 3;           // 8-half chunk of k
      uint4 v = *(const uint4*)(Wh + (size_t)(n0 + f) * 256 + kb + seg * 8);
      *(uint4*)&lW[f * WKP + seg * 8] = v;
    }
    __syncthreads();
    short8 aop[4];
#pragma unroll
    for (int tf = 0; tf < 4; ++tf) {
      int fr = fw + tf * 16 + col;
      aop[tf] = *(const short8*)&lW[fr * WKP + quad * 8];
    }
#pragma unroll
    for (int ts = 0; ts < 4; ++ts) {
      int mi = sw + ts * 16 + col;
      int mp = mi ^ (quad * 16);
      short8 bop;
#pragma unroll
      for (int jx = 0; jx < 8; ++jx)
        bop[jx] = (short)lA[(quad * 8 + jx) * BKP + mp];
#pragma unroll
      for (int tf = 0; tf < 4; ++tf)
        acc[ts][tf] = __builtin_amdgcn_mfma_f32_16x16x32_bf16(
            aop[tf], bop, acc[ts][tf], 0, 0, 0);
    }
    __syncthreads();
  }
  // epilogue: D col=lane&15 -> sample, row=quad*4+reg -> feature; bf16 out
#pragma unroll
  for (int ts = 0; ts < 4; ++ts) {
    int m = m0 + sw + ts * 16 + col;
    int h = m / 400;
    int w = m - h * 400;
    size_t obase = (size_t)(w * Hdim + h) * 256;
#pragma unroll
    for (int tf = 0; tf < 4; ++tf) {
      int f = n0 + fw + tf * 16 + quad * 4;
      float4 bv = *(const float4*)(bias + h * 256 + f);
      ushort4 ov;
      ov.x = f2b(acc[ts][tf][0] + bv.x);
      ov.y = f2b(acc[ts][tf][1] + bv.y);
      ov.z = f2b(acc[ts][tf][2] + bv.z);
      ov.w = f2b(acc[ts][tf][3] + bv.w);
      *(ushort4*)(Couth + obase + f) = ov;
    }
  }
}

// ===================== MFMA flash attention =====================
// grid (400, 2), 256 threads = 4 waves; wave handles head = blockIdx.y*4+wave.
// Q/K/V bf16 [m][256]; O bf16 [m][256].
#define KP 40   // K LDS row pitch (halfs)
#define VP 72   // V^T LDS row pitch (halfs)
#define PP 72   // P LDS row pitch (halfs)
__global__ __launch_bounds__(256) void attn_mfma_kernel(
    const ushort* __restrict__ qh, const ushort* __restrict__ kh,
    const ushort* __restrict__ vh, ushort* __restrict__ obuf)
{
  __shared__ ushort lK[4][64 * KP];
  __shared__ ushort lV[4][32 * VP];
  __shared__ ushort lP[4][16 * PP];
  int b = blockIdx.x;
  int wave = threadIdx.x >> 6;
  int lane = threadIdx.x & 63;
  int head = blockIdx.y * 4 + wave;
  int col = lane & 15, quad = lane >> 4;
  ushort* Kw = lK[wave];
  ushort* Vw = lV[wave];
  ushort* Pw = lP[wave];

  // stage K rows (lane = key) and V transposed
  {
    const ushort* ksrc = kh + ((size_t)(b * 64 + lane)) * 256 + head * 32;
    uint4 k0 = *(const uint4*)(ksrc);
    uint4 k1 = *(const uint4*)(ksrc + 8);
    uint4 k2 = *(const uint4*)(ksrc + 16);
    uint4 k3 = *(const uint4*)(ksrc + 24);
    ushort* kd = Kw + lane * KP;
    *(uint4*)(kd) = k0; *(uint4*)(kd + 8) = k1;
    *(uint4*)(kd + 16) = k2; *(uint4*)(kd + 24) = k3;
    const ushort* vsrc = vh + ((size_t)(b * 64 + lane)) * 256 + head * 32;
    ushort vr[32];
    *(uint4*)(vr) = *(const uint4*)(vsrc);
    *(uint4*)(vr + 8) = *(const uint4*)(vsrc + 8);
    *(uint4*)(vr + 16) = *(const uint4*)(vsrc + 16);
    *(uint4*)(vr + 24) = *(const uint4*)(vsrc + 24);
#pragma unroll
    for (int d = 0; d < 32; ++d) Vw[d * VP + lane] = vr[d];
  }
  __syncthreads();

  const float scl = 0.17677669529663687f;   // 1/sqrt(32)
  for (int qt = 0; qt < 8; ++qt) {
    // Q A-frag straight from global: A[m=col][k=quad*8+j]
    short8 aq = *(const short8*)(qh +
        ((size_t)(b * 128 + qt * 16 + col)) * 256 + head * 32 + quad * 8);
    // QK^T: 4 k-tiles; B frag = K[key=t*16+col][d=quad*8+j]
    floatx4 s0 = {0.f,0.f,0.f,0.f}, s1 = s0, s2 = s0, s3 = s0;
    {
      short8 b0 = *(const short8*)(Kw + (0 * 16 + col) * KP + quad * 8);
      short8 b1 = *(const short8*)(Kw + (1 * 16 + col) * KP + quad * 8);
      short8 b2 = *(const short8*)(Kw + (2 * 16 + col) * KP + quad * 8);
      short8 b3 = *(const short8*)(Kw + (3 * 16 + col) * KP + quad * 8);
      s0 = __builtin_amdgcn_mfma_f32_16x16x32_bf16(aq, b0, s0, 0, 0, 0);
      s1 = __builtin_amdgcn_mfma_f32_16x16x32_bf16(aq, b1, s1, 0, 0, 0);
      s2 = __builtin_amdgcn_mfma_f32_16x16x32_bf16(aq, b2, s2, 0, 0, 0);
      s3 = __builtin_amdgcn_mfma_f32_16x16x32_bf16(aq, b3, s3, 0, 0, 0);
    }
    // softmax in C-layout: row = quad*4+r, col = col+16t
    float e[4][4], mr[4], sm[4];
#pragma unroll
    for (int r = 0; r < 4; ++r) {
      float v0 = s0[r] * scl, v1 = s1[r] * scl;
      float v2 = s2[r] * scl, v3 = s3[r] * scl;
      e[0][r] = v0; e[1][r] = v1; e[2][r] = v2; e[3][r] = v3;
      mr[r] = fmaxf(fmaxf(v0, v1), fmaxf(v2, v3));
    }
#pragma unroll
    for (int mask = 1; mask <= 8; mask <<= 1)
#pragma unroll
      for (int r = 0; r < 4; ++r)
        mr[r] = fmaxf(mr[r], __shfl_xor(mr[r], mask, 64));
#pragma unroll
    for (int r = 0; r < 4; ++r) {
      float acc = 0.f;
#pragma unroll
      for (int t = 0; t < 4; ++t) {
        float ev = __expf(e[t][r] - mr[r]);
        e[t][r] = ev;
        acc += ev;
      }
      sm[r] = acc;
    }
#pragma unroll
    for (int mask = 1; mask <= 8; mask <<= 1)
#pragma unroll
      for (int r = 0; r < 4; ++r)
        sm[r] += __shfl_xor(sm[r], mask, 64);
    // P -> LDS (bf16), row-major [q][key]
#pragma unroll
    for (int t = 0; t < 4; ++t)
#pragma unroll
      for (int r = 0; r < 4; ++r)
        Pw[(quad * 4 + r) * PP + t * 16 + col] = f2b(e[t][r]);
    __syncthreads();
    // PV: A = P[q=col][key=c*32+quad*8+j]; B = V^T[d][key]
    floatx4 o0 = {0.f,0.f,0.f,0.f}, o1 = o0;
#pragma unroll
    for (int c = 0; c < 2; ++c) {
      short8 ap = *(const short8*)(Pw + col * PP + c * 32 + quad * 8);
      short8 v0 = *(const short8*)(Vw + col * VP + c * 32 + quad * 8);
      short8 v1 = *(const short8*)(Vw + (16 + col) * VP + c * 32 + quad * 8);
      o0 = __builtin_amdgcn_mfma_f32_16x16x32_bf16(ap, v0, o0, 0, 0, 0);
      o1 = __builtin_amdgcn_mfma_f32_16x16x32_bf16(ap, v1, o1, 0, 0, 0);
    }
    // normalize (sm rows == O rows: quad*4+r) and store bf16
#pragma unroll
    for (int r = 0; r < 4; ++r) {
      float iv = 1.0f / sm[r];
      size_t row = (size_t)(b * 128 + qt * 16 + quad * 4 + r) * 256 + head * 32;
      obuf[row + col] = f2b(o0[r] * iv);
      obuf[row + 16 + col] = f2b(o1[r] * iv);
    }
    __syncthreads();   // Pw reused next iteration
  }
}

// ===================== GEMM (A M-major fp32): C = A * W^T + biasf ==========
__global__ __launch_bounds__(256) void gemmN_kernel(
    const float* __restrict__ A, const float* __restrict__ Wt,
    const float* __restrict__ biasf, float* __restrict__ Cout, int mode)
{
  __shared__ float As[64][17];
  __shared__ float Ws[16][65];
  int m0 = blockIdx.x * 64;
  int n0 = blockIdx.y * 64;
  int tid = threadIdx.x;
  int tx = tid & 15, ty = tid >> 4;
  float acc[4][4] = {};
  for (int k0 = 0; k0 < 256; k0 += 16) {
    {
      int m = tid >> 2;            // 0..63
      int kq = (tid & 3) << 2;
      float4 v = *(const float4*)(A + (size_t)(m0 + m) * 256 + k0 + kq);
      As[m][kq + 0] = v.x; As[m][kq + 1] = v.y;
      As[m][kq + 2] = v.z; As[m][kq + 3] = v.w;
    }
    {
      int f = tid >> 2;
      int kq = (tid & 3) << 2;
      float4 v = *(const float4*)(Wt + (size_t)(n0 + f) * 256 + k0 + kq);
      Ws[kq + 0][f] = v.x; Ws[kq + 1][f] = v.y;
      Ws[kq + 2][f] = v.z; Ws[kq + 3][f] = v.w;
    }
    __syncthreads();
#pragma unroll
    for (int kk = 0; kk < 16; ++kk) {
      float a[4], b[4];
#pragma unroll
      for (int i = 0; i < 4; ++i) a[i] = As[ty * 4 + i][kk];
#pragma unroll
      for (int jj = 0; jj < 4; ++jj) b[jj] = Ws[kk][tx * 4 + jj];
#pragma unroll
      for (int i = 0; i < 4; ++i)
#pragma unroll
        for (int jj = 0; jj < 4; ++jj) acc[i][jj] += a[i] * b[jj];
    }
    __syncthreads();
  }
#pragma unroll
  for (int i = 0; i < 4; ++i) {
    int m = m0 + ty * 4 + i;
    int f = n0 + tx * 4;
    float4 ov;
    if (mode == 0) {
      float4 bv = *(const float4*)(biasf + f);
      ov.x = acc[i][0] + bv.x; ov.y = acc[i][1] + bv.y;
      ov.z = acc[i][2] + bv.z; ov.w = acc[i][3] + bv.w;
    } else {
      ov.x = acc[i][0]; ov.y = acc[i][1];
      ov.z = acc[i][2]; ov.w = acc[i][3];
    }
    *(float4*)(Cout + (size_t)m * 256 + f) = ov;
  }
}

// ===================== GEMM A[m][k] * B[k][n] (effective weights) ==========
__global__ __launch_bounds__(256) void gemm_ab_kernel(
    const float* __restrict__ in_w, const float* __restrict__ Wq,
    const float* __restrict__ Wk, const float* __restrict__ Wv,
    float* __restrict__ weff)
{
  int z = blockIdx.z;
  const float* A = in_w + (size_t)z * 65536;
  const float* B = (z == 0) ? Wq : ((z == 1) ? Wk : Wv);
  float* C = weff + (size_t)z * 65536;
  __shared__ float As[64][17];
  __shared__ float Bs[16][64];
  int m0 = blockIdx.x * 64;
  int n0 = blockIdx.y * 64;
  int tid = threadIdx.x;
  int tx = tid & 15, ty = tid >> 4;
  float acc[4][4] = {};
  for (int k0 = 0; k0 < 256; k0 += 16) {
    {
      int m = tid >> 2;
      int kq = (tid & 3) << 2;
      float4 v = *(const float4*)(A + (size_t)(m0 + m) * 256 + k0 + kq);
      As[m][kq + 0] = v.x; As[m][kq + 1] = v.y;
      As[m][kq + 2] = v.z; As[m][kq + 3] = v.w;
    }
    {
      int k = tid >> 4;
      int nq = (tid & 15) << 2;
      float4 v = *(const float4*)(B + (size_t)(k0 + k) * 256 + n0 + nq);
      *(float4*)(&Bs[k][nq]) = v;
    }
    __syncthreads();
#pragma unroll
    for (int kk = 0; kk < 16; ++kk) {
      float a[4], b[4];
#pragma unroll
      for (int i = 0; i < 4; ++i) a[i] = As[ty * 4 + i][kk];
#pragma unroll
      for (int jj = 0; jj < 4; ++jj) b[jj] = Bs[kk][tx * 4 + jj];
#pragma unroll
      for (int i = 0; i < 4; ++i)
#pragma unroll
        for (int jj = 0; jj < 4; ++jj) acc[i][jj] += a[i] * b[jj];
    }
    __syncthreads();
  }
#pragma unroll
  for (int i = 0; i < 4; ++i) {
    int m = m0 + ty * 4 + i;
    *(float4*)(C + (size_t)m * 256 + n0 + tx * 4) = *(float4*)&acc[i][0];
  }
}

// ===================== effective biases =====================
__global__ void beff_kernel(const float* __restrict__ in_w, const float* __restrict__ in_b,
                            const float* __restrict__ bq, const float* __restrict__ bk,
                            const float* __restrict__ bv, float* __restrict__ beff)
{
  int z = blockIdx.x;
  int f = threadIdx.x;
  const float* bsrc = (z == 0) ? bq : ((z == 1) ? bk : bv);
  const float* row = in_w + (size_t)(z * 256 + f) * 256;
  float acc = in_b[z * 256 + f];
  for (int e = 0; e < 256; ++e) acc += row[e] * bsrc[e];
  beff[z * 256 + f] = acc;
}

// ===================== per-pixel gather-reduce (lane-split, bf16 out) ======
// 512 threads = 8 sample-lanes x 64 channels; grid (16384 pixels, 4 ch-groups)
__global__ __launch_bounds__(512) void gather_kernel(
    const ushort* __restrict__ obuf, const int* __restrict__ order,
    const int* __restrict__ offsets, const float* __restrict__ cnt,
    ushort* __restrict__ osum)
{
  __shared__ float red[8][64];
  int p = blockIdx.x;
  int c64 = threadIdx.x & 63;
  int l = threadIdx.x >> 6;          // sample lane 0..7
  int c = blockIdx.y * 64 + c64;
  int off = offsets[p];
  int n = (int)cnt[p];
  int end = off + n;
  float acc = 0.0f, acc2 = 0.0f;
  int i = off + l;
  for (; i + 8 < end; i += 16) {
    int m0 = order[i], m1 = order[i + 8];
    acc  += b2f(obuf[(size_t)m0 * 256 + c]);
    acc2 += b2f(obuf[(size_t)m1 * 256 + c]);
  }
  if (i < end) acc += b2f(obuf[(size_t)order[i] * 256 + c]);
  red[l][c64] = acc + acc2;
  __syncthreads();
  if (l == 0) {
    float s = 0.f;
#pragma unroll
    for (int jx = 0; jx < 8; ++jx) s += red[jx][c64];
    osum[(size_t)p * 256 + c] = f2b(s);
  }
}

// ===================== MFMA out-proj: enhT = out_w @ osum^T ================
// out_wh[f][k] bf16, osum[p][k] bf16  ->  enhT[f*PIX + p] fp32
// No LDS: both frags load directly from row-major global (L2-resident).
__global__ __launch_bounds__(256) void mfma_outproj_kernel(
    const ushort* __restrict__ osum, const ushort* __restrict__ out_wh,
    float* __restrict__ enhT)
{
  int p0 = blockIdx.x * 64;
  int lane = threadIdx.x & 63;
  int wave = threadIdx.x >> 6;
  int col = lane & 15, quad = lane >> 4;
  int fw = wave * 64;
  floatx4 acc[4][4];   // [ts(p)][tf(f)]
#pragma unroll
  for (int i = 0; i < 4; ++i)
#pragma unroll
    for (int jx = 0; jx < 4; ++jx) acc[i][jx] = (floatx4){0.f, 0.f, 0.f, 0.f};

  for (int kb = 0; kb < 256; kb += 32) {
    short8 aop[4], bop[4];
#pragma unroll
    for (int tf = 0; tf < 4; ++tf)
      aop[tf] = *(const short8*)(out_wh +
          (size_t)(fw + tf * 16 + col) * 256 + kb + quad * 8);
#pragma unroll
    for (int ts = 0; ts < 4; ++ts)
      bop[ts] = *(const short8*)(osum +
          (size_t)(p0 + ts * 16 + col) * 256 + kb + quad * 8);
#pragma unroll
    for (int ts = 0; ts < 4; ++ts)
#pragma unroll
      for (int tf = 0; tf < 4; ++tf)
        acc[ts][tf] = __builtin_amdgcn_mfma_f32_16x16x32_bf16(
            aop[tf], bop[ts], acc[ts][tf], 0, 0, 0);
  }
  // D: row=quad*4+r -> f, col -> p.  enhT[f][p]
#pragma unroll
  for (int ts = 0; ts < 4; ++ts) {
    int p = p0 + ts * 16 + col;
#pragma unroll
    for (int tf = 0; tf < 4; ++tf) {
      int f = fw + tf * 16 + quad * 4;
#pragma unroll
      for (int r = 0; r < 4; ++r)
        enhT[(size_t)(f + r) * PIX + p] = acc[ts][tf][r];
    }
  }
}

// ===================== residual update / final (elementwise, [c][p]) =======
__global__ __launch_bounds__(256) void update_kernel(
    float* __restrict__ a_cur, const float* __restrict__ enhT,
    const float* __restrict__ cnt, const float* __restrict__ out_b,
    float* __restrict__ outp, int final_mode)
{
  int t = blockIdx.x * 256 + threadIdx.x;   // float4 index
  int base = t * 4;
  int c = base >> 14;
  int p = base & (PIX - 1);
  float ob = out_b[c];
  float4 e = ((const float4*)enhT)[t];
  float4 cn = *(const float4*)(cnt + p);
  float4 v;
  v.x = (e.x + cn.x * ob) / fmaxf(cn.x, 1.0f);
  v.y = (e.y + cn.y * ob) / fmaxf(cn.y, 1.0f);
  v.z = (e.z + cn.z * ob) / fmaxf(cn.z, 1.0f);
  v.w = (e.w + cn.w * ob) / fmaxf(cn.w, 1.0f);
  if (final_mode) {
    float4 a = ((const float4*)a_cur)[t];
    float4 o;
    o.x = a.x + 2.0f * v.x; o.y = a.y + 2.0f * v.y;
    o.z = a.z + 2.0f * v.z; o.w = a.w + 2.0f * v.w;
    ((float4*)outp)[t] = o;
  } else {
    float4 a = ((const float4*)a_cur)[t];
    a.x += v.x; a.y += v.y; a.z += v.z; a.w += v.w;
    ((float4*)a_cur)[t] = a;
  }
}

// ===================== launch =====================
extern "C" void kernel_launch(void* const* d_in, const int* in_sizes, int n_in,
                              void* d_out, int out_size, void* d_ws, size_t ws_size,
                              hipStream_t stream) {
  const float* list_a = (const float*)d_in[0];
  const float* list_b = (const float*)d_in[1];
  const float* rots   = (const float*)d_in[3];
  const float* fxs    = (const float*)d_in[5];
  const float* cxs    = (const float*)d_in[6];
  const float* pos_a  = (const float*)d_in[7];
  const float* pos_b  = (const float*)d_in[8];
  const float* Wq     = (const float*)d_in[9];
  const float* bq     = (const float*)d_in[10];
  const float* Wk     = (const float*)d_in[11];
  const float* bk     = (const float*)d_in[12];
  const float* Wv     = (const float*)d_in[13];
  const float* bv     = (const float*)d_in[14];
  const float* in_w   = (const float*)d_in[15];
  const float* in_b   = (const float*)d_in[16];
  const float* out_w  = (const float*)d_in[17];
  const float* out_b  = (const float*)d_in[18];

  float* ws      = (float*)d_ws;
  float* weff    = ws;                          // 196608 f
  float* beff    = weff + 196608;               // 768 f
  float* qpos    = beff + 768;                  // 32768 f
  float* kpos    = qpos + 32768;                // 16384 f
  float* vpos    = kpos + 16384;                // 16384 f
  float* a_cur   = vpos + 16384;                // 4194304 f
  float* xarr    = a_cur + 4194304;             // 51200 f
  float* yarr    = xarr + 51200;                // 51200 f
  int*   idxarr  = (int*)(yarr + 51200);        // 51200
  float* cnt     = (float*)(idxarr + 51200);    // 16384 f
  int*   cursor  = (int*)(cnt + 16384);         // 16384
  int*   offs    = cursor + 16384;              // 16384
  int*   order   = offs + 16384;                // 51200
  ushort* weffh  = (ushort*)(order + 51200);    // 196608 h
  ushort* out_wh = weffh + 196608;              // 65536 h
  ushort* a_recth = out_wh + 65536;             // 13107200 h (obuf alias)
  ushort* bh     = a_recth + 13107200;          // 6553600 h
  ushort* qh     = bh + 6553600;                // 13107200 h (osum alias)
  ushort* kh     = qh + 13107200;               // 6553600 h (enhT alias ->)
  ushort* vh     = kh + 6553600;                // 6553600 h
  ushort* obufh  = a_recth;                     // alias: a_recth dead after Q-proj
  ushort* osum   = qh;                          // alias: qh dead after attn
  float* enhT    = (float*)kh;                  // alias: kh+vh dead after attn (16.7MB < 26MB)

  hipMemcpyAsync(a_cur, list_a, (size_t)4194304 * sizeof(float),
                 hipMemcpyDeviceToDevice, stream);

  // effective weights + biases (tiny)
  gemm_ab_kernel<<<dim3(4, 4, 3), 256, 0, stream>>>(in_w, Wq, Wk, Wv, weff);
  beff_kernel<<<3, 256, 0, stream>>>(in_w, in_b, bq, bk, bv, beff);
  f2b_kernel<<<192, 256, 0, stream>>>(weff, weffh);
  f2b_kernel<<<64, 256, 0, stream>>>(out_w, out_wh);

  // positional bias tables: pos @ Weff^T + beff
  gemmN_kernel<<<dim3(2, 4), 256, 0, stream>>>(pos_a, weff, beff, qpos, 0);
  gemmN_kernel<<<dim3(1, 4), 256, 0, stream>>>(pos_b, weff + 65536, beff + 256, kpos, 0);
  gemmN_kernel<<<dim3(1, 4), 256, 0, stream>>>(pos_b, weff + 131072, beff + 512, vpos, 0);

  for (int jj = 0; jj < 2; ++jj) {
    int j = jj ? 3 : 0;
    hipMemsetAsync(cnt, 0, (size_t)2 * 16384 * sizeof(float), stream);  // cnt + cursor
    coords_kernel<<<200, 256, 0, stream>>>(rots, fxs, cxs, j, xarr, yarr, idxarr, cnt);
    prefix_kernel<<<1, 256, 0, stream>>>(cnt, offs);
    fill_kernel<<<200, 256, 0, stream>>>(idxarr, offs, cursor, order);
    sample_kernel<<<dim3(200, 256), 256, 0, stream>>>(a_cur, xarr, yarr, a_recth);
    const float* bsrc = list_b + (size_t)j * 6553600;
    f2b_kernel<<<6400, 256, 0, stream>>>(bsrc, bh);
    // MFMA projections (bf16 out)
    mfma_gemmT_kernel<<<dim3(400, 2), 256, 0, stream>>>(a_recth, MS, weffh, qpos, qh, 128);
    mfma_gemmT_kernel<<<dim3(200, 2), 256, 0, stream>>>(bh, MB, weffh + 65536, kpos, kh, 64);
    mfma_gemmT_kernel<<<dim3(200, 2), 256, 0, stream>>>(bh, MB, weffh + 131072, vpos, vh, 64);
    // MFMA flash attention (O bf16 into obufh = a_recth region)
    attn_mfma_kernel<<<dim3(400, 2), 256, 0, stream>>>(qh, kh, vh, obufh);
    // per-pixel lane-split reduction of O (bf16 osum)
    gather_kernel<<<dim3(16384, 4), 512, 0, stream>>>(obufh, order, offs, cnt, osum);
    // MFMA out-proj directly into transposed layout [c][p]
    mfma_outproj_kernel<<<256, 256, 0, stream>>>(osum, out_wh, enhT);
    update_kernel<<<4096, 256, 0, stream>>>(a_cur, enhT, cnt, out_b,
                                            jj ? (float*)d_out : nullptr, jj);
  }
}

// Round 6
// 783.475 us; speedup vs baseline: 3.2651x; 1.2059x over previous
//
#include <hip/hip_runtime.h>

// Problem constants
// a: (256,128,128)  b: (4,256,64,400)  E=256 NH=8 DH=32  B=400 Lq=128 Lk=64
#define PIX 16384          // 128*128
#define MS 51200           // H1*W2 samples
#define MB 25600           // H2*W2

typedef __attribute__((ext_vector_type(8))) short short8;
typedef __attribute__((ext_vector_type(4))) float floatx4;

__device__ inline ushort f2b(float x) {
  uint u = __float_as_uint(x);
  return (ushort)((u + 0x7fffu + ((u >> 16) & 1u)) >> 16);
}
__device__ inline float b2f(ushort u) {
  return __uint_as_float(((uint)u) << 16);
}

// ===================== coords: x,y, scatter idx, counts =====================
__global__ __launch_bounds__(256) void coords_kernel(
    const float* __restrict__ rots, const float* __restrict__ fxs,
    const float* __restrict__ cxs, int j,
    float* __restrict__ xarr, float* __restrict__ yarr,
    int* __restrict__ idxarr, float* __restrict__ cnt)
{
  int s = blockIdx.x * 256 + threadIdx.x;      // 0..51199, s = h*400 + w
  int h = s / 400;
  int w = s - h * 400;
  float fx = fxs[j], cx = cxs[j];
  const float* R = rots + j * 9;
  float cr = R[3];        // rots[1][0]
  float sr = -R[0];       // -rots[0][0]
  float t = (2.0f * (float)w + 1.0f - cx) / fx;      // tan(ang)
  float inv = 1.0f / sqrtf(1.0f + t * t);            // cos(ang)
  float ca = (cr + sr * t) * inv;                    // cr*cos + sr*sin
  float sa = (cr * t - sr) * inv;                    // -sr*cos + cr*sin
  float rad = ((float)h * (1.0f / 127.0f)) * 90.50966799187808f;
  float x = 64.0f + rad * ca;
  float y = 64.0f - rad * sa;
  xarr[s] = x;
  yarr[s] = y;
  int xi = (int)fminf(fmaxf(rintf(x), 0.0f), 127.0f);
  int yi = (int)fminf(fmaxf(rintf(y), 0.0f), 127.0f);
  int pix = yi * 128 + xi;
  idxarr[s] = pix;
  atomicAdd(&cnt[pix], 1.0f);
}

// ===================== prefix scan over pixel counts =====================
__global__ __launch_bounds__(256) void prefix_kernel(
    const float* __restrict__ cnt, int* __restrict__ offsets)
{
  __shared__ int sh[256];
  int t = threadIdx.x;
  int base = t * 64;
  int sum = 0;
  for (int i = 0; i < 64; ++i) sum += (int)cnt[base + i];
  sh[t] = sum;
  __syncthreads();
  for (int d = 1; d < 256; d <<= 1) {
    int v = (t >= d) ? sh[t - d] : 0;
    __syncthreads();
    sh[t] += v;
    __syncthreads();
  }
  int run = sh[t] - sum;   // exclusive prefix for this thread's chunk
  for (int i = 0; i < 64; ++i) {
    offsets[base + i] = run;
    run += (int)cnt[base + i];
  }
}

// ===================== fill sorted sample lists =====================
__global__ __launch_bounds__(256) void fill_kernel(
    const int* __restrict__ idxarr, const int* __restrict__ offsets,
    int* __restrict__ cursor, int* __restrict__ order, int* __restrict__ pixs)
{
  int s = blockIdx.x * 256 + threadIdx.x;
  int pix = idxarr[s];
  int pos = offsets[pix] + atomicAdd(&cursor[pix], 1);
  // store the attention-output row index m = w*128 + h  (s = h*400 + w)
  order[pos] = (s % 400) * 128 + (s / 400);
  pixs[pos] = pix;
}

// ===================== bilinear sampler: a_recth[c][s] (bf16) ==============
__global__ __launch_bounds__(256) void sample_kernel(
    const float* __restrict__ src, const float* __restrict__ xarr,
    const float* __restrict__ yarr, ushort* __restrict__ a_recth)
{
  int s = blockIdx.x * 256 + threadIdx.x;   // sample index
  int c = blockIdx.y;                       // channel
  float x = fminf(fmaxf(xarr[s], 0.0f), 127.0f);
  float y = fminf(fmaxf(yarr[s], 0.0f), 127.0f);
  float x0f = floorf(x), y0f = floorf(y);
  int x0 = (int)x0f, y0 = (int)y0f;
  int x1 = min(x0 + 1, 127), y1 = min(y0 + 1, 127);
  float wx = x - x0f, wy = y - y0f;
  const float* img = src + (size_t)c * PIX;
  float v00 = img[y0 * 128 + x0];
  float v01 = img[y0 * 128 + x1];
  float v10 = img[y1 * 128 + x0];
  float v11 = img[y1 * 128 + x1];
  float val = v00 * (1.0f - wx) * (1.0f - wy) + v01 * wx * (1.0f - wy)
            + v10 * (1.0f - wx) * wy + v11 * wx * wy;
  a_recth[(size_t)c * MS + s] = f2b(val);
}

// ===================== f32 -> bf16 bulk convert (float4-wide) ==============
__global__ __launch_bounds__(256) void f2b_kernel(
    const float* __restrict__ in, ushort* __restrict__ out)
{
  int t = blockIdx.x * 256 + threadIdx.x;
  float4 v = ((const float4*)in)[t];
  ushort4 o;
  o.x = f2b(v.x); o.y = f2b(v.y); o.z = f2b(v.z); o.w = f2b(v.w);
  ((ushort4*)out)[t] = o;
}

// ===================== MFMA GEMM: C = A^T(K-major bf16) @ W^T(bf16) ========
// Ah[k][m] stride Astride; Wh[f][k]; bias fp32 [h][256];
// out row permute: m = h*400+w -> row = w*Hdim+h;  Couth[row*256+f] bf16
#define BKP 144   // LDS A row stride in halfs (k-row -> 128 m + swizzle pad)
#define WKP 40    // LDS W row stride in halfs (32 k + pad)
__global__ __launch_bounds__(256) void mfma_gemmT_kernel(
    const ushort* __restrict__ Ah, int Astride,
    const ushort* __restrict__ Wh, const float* __restrict__ bias,
    ushort* __restrict__ Couth, int Hdim)
{
  __shared__ ushort lA[32 * BKP];   // [k_local][m' (xor-swizzled)]
  __shared__ ushort lW[128 * WKP];  // [f_local][k_local]
  int m0 = blockIdx.x * 128;
  int n0 = blockIdx.y * 128;
  int tid = threadIdx.x;
  int lane = tid & 63;
  int wave = tid >> 6;
  int col = lane & 15;
  int quad = lane >> 4;
  int sw = (wave & 1) * 64;     // wave sample-offset in tile
  int fw = (wave >> 1) * 64;    // wave feature-offset in tile
  floatx4 acc[4][4];
#pragma unroll
  for (int i = 0; i < 4; ++i)
#pragma unroll
    for (int jx = 0; jx < 4; ++jx) acc[i][jx] = (floatx4){0.f, 0.f, 0.f, 0.f};

  for (int kb = 0; kb < 256; kb += 32) {
#pragma unroll
    for (int half = 0; half < 2; ++half) {
      int L = tid + half * 256;
      int r = L >> 4;            // k row 0..31
      int c = L & 15;            // 16-byte m chunk
      uint4 v = *(const uint4*)(Ah + (size_t)(kb + r) * Astride + m0 + c * 8);
      int mp = (c * 8) ^ ((r >> 3) * 16);
      *(uint4*)&lA[r * BKP + mp] = v;
    }
#pragma unroll
    for (int half = 0; half < 2; ++half) {
      int L = tid + half * 256;
      int f = L >> 2;            // 0..127
      int seg = L & 3;           // 8-half chunk of k
      uint4 v = *(const uint4*)(Wh + (size_t)(n0 + f) * 256 + kb + seg * 8);
      *(uint4*)&lW[f * WKP + seg * 8] = v;
    }
    __syncthreads();
    short8 aop[4];
#pragma unroll
    for (int tf = 0; tf < 4; ++tf) {
      int fr = fw + tf * 16 + col;
      aop[tf] = *(const short8*)&lW[fr * WKP + quad * 8];
    }
#pragma unroll
    for (int ts = 0; ts < 4; ++ts) {
      int mi = sw + ts * 16 + col;
      int mp = mi ^ (quad * 16);
      short8 bop;
#pragma unroll
      for (int jx = 0; jx < 8; ++jx)
        bop[jx] = (short)lA[(quad * 8 + jx) * BKP + mp];
#pragma unroll
      for (int tf = 0; tf < 4; ++tf)
        acc[ts][tf] = __builtin_amdgcn_mfma_f32_16x16x32_bf16(
            aop[tf], bop, acc[ts][tf], 0, 0, 0);
    }
    __syncthreads();
  }
  // epilogue: D col=lane&15 -> sample, row=quad*4+reg -> feature; bf16 out
#pragma unroll
  for (int ts = 0; ts < 4; ++ts) {
    int m = m0 + sw + ts * 16 + col;
    int h = m / 400;
    int w = m - h * 400;
    size_t obase = (size_t)(w * Hdim + h) * 256;
#pragma unroll
    for (int tf = 0; tf < 4; ++tf) {
      int f = n0 + fw + tf * 16 + quad * 4;
      float4 bv = *(const float4*)(bias + h * 256 + f);
      ushort4 ov;
      ov.x = f2b(acc[ts][tf][0] + bv.x);
      ov.y = f2b(acc[ts][tf][1] + bv.y);
      ov.z = f2b(acc[ts][tf][2] + bv.z);
      ov.w = f2b(acc[ts][tf][3] + bv.w);
      *(ushort4*)(Couth + obase + f) = ov;
    }
  }
}

// ===================== MFMA flash attention =====================
// grid (400, 2), 256 threads = 4 waves; wave handles head = blockIdx.y*4+wave.
// Q/K/V bf16 [m][256]; O bf16 [m][256].
#define KP 40   // K LDS row pitch (halfs)
#define VP 72   // V^T LDS row pitch (halfs)
#define PP 72   // P LDS row pitch (halfs)
__global__ __launch_bounds__(256) void attn_mfma_kernel(
    const ushort* __restrict__ qh, const ushort* __restrict__ kh,
    const ushort* __restrict__ vh, ushort* __restrict__ obuf)
{
  __shared__ ushort lK[4][64 * KP];
  __shared__ ushort lV[4][32 * VP];
  __shared__ ushort lP[4][16 * PP];
  int b = blockIdx.x;
  int wave = threadIdx.x >> 6;
  int lane = threadIdx.x & 63;
  int head = blockIdx.y * 4 + wave;
  int col = lane & 15, quad = lane >> 4;
  ushort* Kw = lK[wave];
  ushort* Vw = lV[wave];
  ushort* Pw = lP[wave];

  // stage K rows (lane = key) and V transposed
  {
    const ushort* ksrc = kh + ((size_t)(b * 64 + lane)) * 256 + head * 32;
    uint4 k0 = *(const uint4*)(ksrc);
    uint4 k1 = *(const uint4*)(ksrc + 8);
    uint4 k2 = *(const uint4*)(ksrc + 16);
    uint4 k3 = *(const uint4*)(ksrc + 24);
    ushort* kd = Kw + lane * KP;
    *(uint4*)(kd) = k0; *(uint4*)(kd + 8) = k1;
    *(uint4*)(kd + 16) = k2; *(uint4*)(kd + 24) = k3;
    const ushort* vsrc = vh + ((size_t)(b * 64 + lane)) * 256 + head * 32;
    ushort vr[32];
    *(uint4*)(vr) = *(const uint4*)(vsrc);
    *(uint4*)(vr + 8) = *(const uint4*)(vsrc + 8);
    *(uint4*)(vr + 16) = *(const uint4*)(vsrc + 16);
    *(uint4*)(vr + 24) = *(const uint4*)(vsrc + 24);
#pragma unroll
    for (int d = 0; d < 32; ++d) Vw[d * VP + lane] = vr[d];
  }
  __syncthreads();

  const float scl = 0.17677669529663687f;   // 1/sqrt(32)
  for (int qt = 0; qt < 8; ++qt) {
    // Q A-frag straight from global: A[m=col][k=quad*8+j]
    short8 aq = *(const short8*)(qh +
        ((size_t)(b * 128 + qt * 16 + col)) * 256 + head * 32 + quad * 8);
    // QK^T: 4 k-tiles; B frag = K[key=t*16+col][d=quad*8+j]
    floatx4 s0 = {0.f,0.f,0.f,0.f}, s1 = s0, s2 = s0, s3 = s0;
    {
      short8 b0 = *(const short8*)(Kw + (0 * 16 + col) * KP + quad * 8);
      short8 b1 = *(const short8*)(Kw + (1 * 16 + col) * KP + quad * 8);
      short8 b2 = *(const short8*)(Kw + (2 * 16 + col) * KP + quad * 8);
      short8 b3 = *(const short8*)(Kw + (3 * 16 + col) * KP + quad * 8);
      s0 = __builtin_amdgcn_mfma_f32_16x16x32_bf16(aq, b0, s0, 0, 0, 0);
      s1 = __builtin_amdgcn_mfma_f32_16x16x32_bf16(aq, b1, s1, 0, 0, 0);
      s2 = __builtin_amdgcn_mfma_f32_16x16x32_bf16(aq, b2, s2, 0, 0, 0);
      s3 = __builtin_amdgcn_mfma_f32_16x16x32_bf16(aq, b3, s3, 0, 0, 0);
    }
    // softmax in C-layout: row = quad*4+r, col = col+16t
    float e[4][4], mr[4], sm[4];
#pragma unroll
    for (int r = 0; r < 4; ++r) {
      float v0 = s0[r] * scl, v1 = s1[r] * scl;
      float v2 = s2[r] * scl, v3 = s3[r] * scl;
      e[0][r] = v0; e[1][r] = v1; e[2][r] = v2; e[3][r] = v3;
      mr[r] = fmaxf(fmaxf(v0, v1), fmaxf(v2, v3));
    }
#pragma unroll
    for (int mask = 1; mask <= 8; mask <<= 1)
#pragma unroll
      for (int r = 0; r < 4; ++r)
        mr[r] = fmaxf(mr[r], __shfl_xor(mr[r], mask, 64));
#pragma unroll
    for (int r = 0; r < 4; ++r) {
      float acc = 0.f;
#pragma unroll
      for (int t = 0; t < 4; ++t) {
        float ev = __expf(e[t][r] - mr[r]);
        e[t][r] = ev;
        acc += ev;
      }
      sm[r] = acc;
    }
#pragma unroll
    for (int mask = 1; mask <= 8; mask <<= 1)
#pragma unroll
      for (int r = 0; r < 4; ++r)
        sm[r] += __shfl_xor(sm[r], mask, 64);
    // P -> LDS (bf16), row-major [q][key]
#pragma unroll
    for (int t = 0; t < 4; ++t)
#pragma unroll
      for (int r = 0; r < 4; ++r)
        Pw[(quad * 4 + r) * PP + t * 16 + col] = f2b(e[t][r]);
    __syncthreads();
    // PV: A = P[q=col][key=c*32+quad*8+j]; B = V^T[d][key]
    floatx4 o0 = {0.f,0.f,0.f,0.f}, o1 = o0;
#pragma unroll
    for (int c = 0; c < 2; ++c) {
      short8 ap = *(const short8*)(Pw + col * PP + c * 32 + quad * 8);
      short8 v0 = *(const short8*)(Vw + col * VP + c * 32 + quad * 8);
      short8 v1 = *(const short8*)(Vw + (16 + col) * VP + c * 32 + quad * 8);
      o0 = __builtin_amdgcn_mfma_f32_16x16x32_bf16(ap, v0, o0, 0, 0, 0);
      o1 = __builtin_amdgcn_mfma_f32_16x16x32_bf16(ap, v1, o1, 0, 0, 0);
    }
    // normalize (sm rows == O rows: quad*4+r) and store bf16
#pragma unroll
    for (int r = 0; r < 4; ++r) {
      float iv = 1.0f / sm[r];
      size_t row = (size_t)(b * 128 + qt * 16 + quad * 4 + r) * 256 + head * 32;
      obuf[row + col] = f2b(o0[r] * iv);
      obuf[row + 16 + col] = f2b(o1[r] * iv);
    }
    __syncthreads();   // Pw reused next iteration
  }
}

// ===================== GEMM (A M-major fp32): C = A * W^T + biasf ==========
__global__ __launch_bounds__(256) void gemmN_kernel(
    const float* __restrict__ A, const float* __restrict__ Wt,
    const float* __restrict__ biasf, float* __restrict__ Cout, int mode)
{
  __shared__ float As[64][17];
  __shared__ float Ws[16][65];
  int m0 = blockIdx.x * 64;
  int n0 = blockIdx.y * 64;
  int tid = threadIdx.x;
  int tx = tid & 15, ty = tid >> 4;
  float acc[4][4] = {};
  for (int k0 = 0; k0 < 256; k0 += 16) {
    {
      int m = tid >> 2;            // 0..63
      int kq = (tid & 3) << 2;
      float4 v = *(const float4*)(A + (size_t)(m0 + m) * 256 + k0 + kq);
      As[m][kq + 0] = v.x; As[m][kq + 1] = v.y;
      As[m][kq + 2] = v.z; As[m][kq + 3] = v.w;
    }
    {
      int f = tid >> 2;
      int kq = (tid & 3) << 2;
      float4 v = *(const float4*)(Wt + (size_t)(n0 + f) * 256 + k0 + kq);
      Ws[kq + 0][f] = v.x; Ws[kq + 1][f] = v.y;
      Ws[kq + 2][f] = v.z; Ws[kq + 3][f] = v.w;
    }
    __syncthreads();
#pragma unroll
    for (int kk = 0; kk < 16; ++kk) {
      float a[4], b[4];
#pragma unroll
      for (int i = 0; i < 4; ++i) a[i] = As[ty * 4 + i][kk];
#pragma unroll
      for (int jj = 0; jj < 4; ++jj) b[jj] = Ws[kk][tx * 4 + jj];
#pragma unroll
      for (int i = 0; i < 4; ++i)
#pragma unroll
        for (int jj = 0; jj < 4; ++jj) acc[i][jj] += a[i] * b[jj];
    }
    __syncthreads();
  }
#pragma unroll
  for (int i = 0; i < 4; ++i) {
    int m = m0 + ty * 4 + i;
    int f = n0 + tx * 4;
    float4 ov;
    if (mode == 0) {
      float4 bv = *(const float4*)(biasf + f);
      ov.x = acc[i][0] + bv.x; ov.y = acc[i][1] + bv.y;
      ov.z = acc[i][2] + bv.z; ov.w = acc[i][3] + bv.w;
    } else {
      ov.x = acc[i][0]; ov.y = acc[i][1];
      ov.z = acc[i][2]; ov.w = acc[i][3];
    }
    *(float4*)(Cout + (size_t)m * 256 + f) = ov;
  }
}

// ===================== GEMM A[m][k] * B[k][n] (effective weights) ==========
__global__ __launch_bounds__(256) void gemm_ab_kernel(
    const float* __restrict__ in_w, const float* __restrict__ Wq,
    const float* __restrict__ Wk, const float* __restrict__ Wv,
    float* __restrict__ weff)
{
  int z = blockIdx.z;
  const float* A = in_w + (size_t)z * 65536;
  const float* B = (z == 0) ? Wq : ((z == 1) ? Wk : Wv);
  float* C = weff + (size_t)z * 65536;
  __shared__ float As[64][17];
  __shared__ float Bs[16][64];
  int m0 = blockIdx.x * 64;
  int n0 = blockIdx.y * 64;
  int tid = threadIdx.x;
  int tx = tid & 15, ty = tid >> 4;
  float acc[4][4] = {};
  for (int k0 = 0; k0 < 256; k0 += 16) {
    {
      int m = tid >> 2;
      int kq = (tid & 3) << 2;
      float4 v = *(const float4*)(A + (size_t)(m0 + m) * 256 + k0 + kq);
      As[m][kq + 0] = v.x; As[m][kq + 1] = v.y;
      As[m][kq + 2] = v.z; As[m][kq + 3] = v.w;
    }
    {
      int k = tid >> 4;
      int nq = (tid & 15) << 2;
      float4 v = *(const float4*)(B + (size_t)(k0 + k) * 256 + n0 + nq);
      *(float4*)(&Bs[k][nq]) = v;
    }
    __syncthreads();
#pragma unroll
    for (int kk = 0; kk < 16; ++kk) {
      float a[4], b[4];
#pragma unroll
      for (int i = 0; i < 4; ++i) a[i] = As[ty * 4 + i][kk];
#pragma unroll
      for (int jj = 0; jj < 4; ++jj) b[jj] = Bs[kk][tx * 4 + jj];
#pragma unroll
      for (int i = 0; i < 4; ++i)
#pragma unroll
        for (int jj = 0; jj < 4; ++jj) acc[i][jj] += a[i] * b[jj];
    }
    __syncthreads();
  }
#pragma unroll
  for (int i = 0; i < 4; ++i) {
    int m = m0 + ty * 4 + i;
    *(float4*)(C + (size_t)m * 256 + n0 + tx * 4) = *(float4*)&acc[i][0];
  }
}

// ===================== effective biases =====================
__global__ void beff_kernel(const float* __restrict__ in_w, const float* __restrict__ in_b,
                            const float* __restrict__ bq, const float* __restrict__ bk,
                            const float* __restrict__ bv, float* __restrict__ beff)
{
  int z = blockIdx.x;
  int f = threadIdx.x;
  const float* bsrc = (z == 0) ? bq : ((z == 1) ? bk : bv);
  const float* row = in_w + (size_t)(z * 256 + f) * 256;
  float acc = in_b[z * 256 + f];
  for (int e = 0; e < 256; ++e) acc += row[e] * bsrc[e];
  beff[z * 256 + f] = acc;
}

// ===================== segmented reduction over sorted samples =============
// 800 blocks x 256 threads; block = 64 consecutive sorted samples, thread = channel.
// Complete runs (whole pixel segment inside chunk) -> plain store;
// chunk-edge partial runs -> atomicAdd into zeroed osum.
#define CH 64
__global__ __launch_bounds__(256) void segred_kernel(
    const ushort* __restrict__ obuf, const int* __restrict__ order,
    const int* __restrict__ pixs, float* __restrict__ osum)
{
  __shared__ int lm[CH];
  __shared__ int lp[CH + 2];   // [0]=prev guard, [1..CH]=pix, [CH+1]=next guard
  int s0 = blockIdx.x * CH;
  int t = threadIdx.x;
  if (t < CH) {
    lm[t] = order[s0 + t];
    lp[t + 1] = pixs[s0 + t];
  } else if (t == CH) {
    lp[0] = (s0 > 0) ? pixs[s0 - 1] : -1;
  } else if (t == CH + 1) {
    lp[CH + 1] = (s0 + CH < MS) ? pixs[s0 + CH] : -2;
  }
  __syncthreads();
  int c = t;   // channel
  float va[8];
#pragma unroll
  for (int k = 0; k < 8; ++k)
    va[k] = b2f(obuf[(size_t)lm[k] * 256 + c]);
  float acc = 0.0f;
  int runBegin = 0;
#pragma unroll
  for (int i = 0; i < CH; ++i) {
    float v = va[i & 7];
    if (i + 8 < CH) va[i & 7] = b2f(obuf[(size_t)lm[i + 8] * 256 + c]);
    acc += v;
    int p = lp[i + 1];
    bool last = (i == CH - 1);
    if (last || p != lp[i + 2]) {
      bool pBeg = (runBegin == 0) && (p == lp[0]);
      bool pEnd = last && (p == lp[CH + 1]);
      float* dst = osum + (size_t)p * 256 + c;
      if (pBeg || pEnd) atomicAdd(dst, acc);
      else *dst = acc;
      acc = 0.0f;
      runBegin = i + 1;
    }
  }
}

// ===================== MFMA out-proj: enhT = out_w @ osum^T ================
// out_wh[f][k] bf16, osum[p][k] fp32 (converted in-register) -> enhT[f*PIX+p]
__global__ __launch_bounds__(256) void mfma_outproj_kernel(
    const float* __restrict__ osum, const ushort* __restrict__ out_wh,
    float* __restrict__ enhT)
{
  int p0 = blockIdx.x * 64;
  int lane = threadIdx.x & 63;
  int wave = threadIdx.x >> 6;
  int col = lane & 15, quad = lane >> 4;
  int fw = wave * 64;
  floatx4 acc[4][4];   // [ts(p)][tf(f)]
#pragma unroll
  for (int i = 0; i < 4; ++i)
#pragma unroll
    for (int jx = 0; jx < 4; ++jx) acc[i][jx] = (floatx4){0.f, 0.f, 0.f, 0.f};

  for (int kb = 0; kb < 256; kb += 32) {
    short8 aop[4], bop[4];
#pragma unroll
    for (int tf = 0; tf < 4; ++tf)
      aop[tf] = *(const short8*)(out_wh +
          (size_t)(fw + tf * 16 + col) * 256 + kb + quad * 8);
#pragma unroll
    for (int ts = 0; ts < 4; ++ts) {
      const float* brow = osum + (size_t)(p0 + ts * 16 + col) * 256 + kb + quad * 8;
      float4 f0 = *(const float4*)brow;
      float4 f1 = *(const float4*)(brow + 4);
      short8 bv;
      bv[0] = (short)f2b(f0.x); bv[1] = (short)f2b(f0.y);
      bv[2] = (short)f2b(f0.z); bv[3] = (short)f2b(f0.w);
      bv[4] = (short)f2b(f1.x); bv[5] = (short)f2b(f1.y);
      bv[6] = (short)f2b(f1.z); bv[7] = (short)f2b(f1.w);
      bop[ts] = bv;
    }
#pragma unroll
    for (int ts = 0; ts < 4; ++ts)
#pragma unroll
      for (int tf = 0; tf < 4; ++tf)
        acc[ts][tf] = __builtin_amdgcn_mfma_f32_16x16x32_bf16(
            aop[tf], bop[ts], acc[ts][tf], 0, 0, 0);
  }
  // D: row=quad*4+r -> f, col -> p.  enhT[f][p]
#pragma unroll
  for (int ts = 0; ts < 4; ++ts) {
    int p = p0 + ts * 16 + col;
#pragma unroll
    for (int tf = 0; tf < 4; ++tf) {
      int f = fw + tf * 16 + quad * 4;
#pragma unroll
      for (int r = 0; r < 4; ++r)
        enhT[(size_t)(f + r) * PIX + p] = acc[ts][tf][r];
    }
  }
}

// ===================== residual update / final (elementwise, [c][p]) =======
// adst[t] = asrc[t] + scale * (enhT + cnt*out_b)/max(cnt,1)
__global__ __launch_bounds__(256) void update_kernel(
    const float* __restrict__ asrc, float* __restrict__ adst,
    const float* __restrict__ enhT, const float* __restrict__ cnt,
    const float* __restrict__ out_b, float scale)
{
  int t = blockIdx.x * 256 + threadIdx.x;   // float4 index
  int base = t * 4;
  int c = base >> 14;
  int p = base & (PIX - 1);
  float ob = out_b[c];
  float4 e = ((const float4*)enhT)[t];
  float4 cn = *(const float4*)(cnt + p);
  float4 a = ((const float4*)asrc)[t];
  float4 o;
  o.x = a.x + scale * (e.x + cn.x * ob) / fmaxf(cn.x, 1.0f);
  o.y = a.y + scale * (e.y + cn.y * ob) / fmaxf(cn.y, 1.0f);
  o.z = a.z + scale * (e.z + cn.z * ob) / fmaxf(cn.z, 1.0f);
  o.w = a.w + scale * (e.w + cn.w * ob) / fmaxf(cn.w, 1.0f);
  ((float4*)adst)[t] = o;
}

// ===================== launch =====================
extern "C" void kernel_launch(void* const* d_in, const int* in_sizes, int n_in,
                              void* d_out, int out_size, void* d_ws, size_t ws_size,
                              hipStream_t stream) {
  const float* list_a = (const float*)d_in[0];
  const float* list_b = (const float*)d_in[1];
  const float* rots   = (const float*)d_in[3];
  const float* fxs    = (const float*)d_in[5];
  const float* cxs    = (const float*)d_in[6];
  const float* pos_a  = (const float*)d_in[7];
  const float* pos_b  = (const float*)d_in[8];
  const float* Wq     = (const float*)d_in[9];
  const float* bq     = (const float*)d_in[10];
  const float* Wk     = (const float*)d_in[11];
  const float* bk     = (const float*)d_in[12];
  const float* Wv     = (const float*)d_in[13];
  const float* bv     = (const float*)d_in[14];
  const float* in_w   = (const float*)d_in[15];
  const float* in_b   = (const float*)d_in[16];
  const float* out_w  = (const float*)d_in[17];
  const float* out_b  = (const float*)d_in[18];

  float* ws      = (float*)d_ws;
  float* weff    = ws;                          // 196608 f
  float* beff    = weff + 196608;               // 768 f
  float* qpos    = beff + 768;                  // 32768 f
  float* kpos    = qpos + 32768;                // 16384 f
  float* vpos    = kpos + 16384;                // 16384 f
  float* a_cur   = vpos + 16384;                // 4194304 f
  float* xarr    = a_cur + 4194304;             // 51200 f
  float* yarr    = xarr + 51200;                // 51200 f
  int*   idxarr  = (int*)(yarr + 51200);        // 51200
  float* cnt     = (float*)(idxarr + 51200);    // 16384 f
  int*   cursor  = (int*)(cnt + 16384);         // 16384
  int*   offs    = cursor + 16384;              // 16384
  int*   order   = offs + 16384;                // 51200
  int*   pixs    = order + 51200;               // 51200
  float* osum    = (float*)(pixs + 51200);      // 4194304 f
  ushort* weffh  = (ushort*)(osum + 4194304);   // 196608 h
  ushort* out_wh = weffh + 196608;              // 65536 h
  ushort* a_recth = out_wh + 65536;             // 13107200 h (obuf alias)
  ushort* bh     = a_recth + 13107200;          // 6553600 h
  ushort* qh     = bh + 6553600;                // 13107200 h
  ushort* kh     = qh + 13107200;               // 6553600 h (enhT alias ->)
  ushort* vh     = kh + 6553600;                // 6553600 h
  ushort* obufh  = a_recth;                     // alias: a_recth dead after Q-proj
  float* enhT    = (float*)kh;                  // alias: kh+vh dead after attn

  // effective weights + biases (tiny)
  gemm_ab_kernel<<<dim3(4, 4, 3), 256, 0, stream>>>(in_w, Wq, Wk, Wv, weff);
  beff_kernel<<<3, 256, 0, stream>>>(in_w, in_b, bq, bk, bv, beff);
  f2b_kernel<<<192, 256, 0, stream>>>(weff, weffh);
  f2b_kernel<<<64, 256, 0, stream>>>(out_w, out_wh);

  // positional bias tables: pos @ Weff^T + beff
  gemmN_kernel<<<dim3(2, 4), 256, 0, stream>>>(pos_a, weff, beff, qpos, 0);
  gemmN_kernel<<<dim3(1, 4), 256, 0, stream>>>(pos_b, weff + 65536, beff + 256, kpos, 0);
  gemmN_kernel<<<dim3(1, 4), 256, 0, stream>>>(pos_b, weff + 131072, beff + 512, vpos, 0);

  for (int jj = 0; jj < 2; ++jj) {
    int j = jj ? 3 : 0;
    const float* asrc = jj ? a_cur : list_a;
    hipMemsetAsync(cnt, 0, (size_t)2 * 16384 * sizeof(float), stream);  // cnt + cursor
    hipMemsetAsync(osum, 0, (size_t)4194304 * sizeof(float), stream);
    coords_kernel<<<200, 256, 0, stream>>>(rots, fxs, cxs, j, xarr, yarr, idxarr, cnt);
    prefix_kernel<<<1, 256, 0, stream>>>(cnt, offs);
    fill_kernel<<<200, 256, 0, stream>>>(idxarr, offs, cursor, order, pixs);
    sample_kernel<<<dim3(200, 256), 256, 0, stream>>>(asrc, xarr, yarr, a_recth);
    const float* bsrc = list_b + (size_t)j * 6553600;
    f2b_kernel<<<6400, 256, 0, stream>>>(bsrc, bh);
    // MFMA projections (bf16 out)
    mfma_gemmT_kernel<<<dim3(400, 2), 256, 0, stream>>>(a_recth, MS, weffh, qpos, qh, 128);
    mfma_gemmT_kernel<<<dim3(200, 2), 256, 0, stream>>>(bh, MB, weffh + 65536, kpos, kh, 64);
    mfma_gemmT_kernel<<<dim3(200, 2), 256, 0, stream>>>(bh, MB, weffh + 131072, vpos, vh, 64);
    // MFMA flash attention (O bf16 into obufh = a_recth region)
    attn_mfma_kernel<<<dim3(400, 2), 256, 0, stream>>>(qh, kh, vh, obufh);
    // segmented reduction of O over sorted samples -> osum fp32
    segred_kernel<<<800, 256, 0, stream>>>(obufh, order, pixs, osum);
    // MFMA out-proj directly into transposed layout [c][p]
    mfma_outproj_kernel<<<256, 256, 0, stream>>>(osum, out_wh, enhT);
    update_kernel<<<4096, 256, 0, stream>>>(asrc, jj ? (float*)d_out : a_cur,
                                            enhT, cnt, out_b, jj ? 2.0f : 1.0f);
  }
}

// Round 7
// 719.766 us; speedup vs baseline: 3.5541x; 1.0885x over previous
//
#include <hip/hip_runtime.h>

// Problem constants
// a: (256,128,128)  b: (4,256,64,400)  E=256 NH=8 DH=32  B=400 Lq=128 Lk=64
#define PIX 16384          // 128*128
#define MS 51200           // H1*W2 samples
#define MB 25600           // H2*W2

typedef __attribute__((ext_vector_type(8))) short short8;
typedef __attribute__((ext_vector_type(4))) float floatx4;

__device__ inline ushort f2b(float x) {
  uint u = __float_as_uint(x);
  return (ushort)((u + 0x7fffu + ((u >> 16) & 1u)) >> 16);
}
__device__ inline float b2f(ushort u) {
  return __uint_as_float(((uint)u) << 16);
}

// ===================== coords: x,y, scatter idx, counts =====================
__global__ __launch_bounds__(256) void coords_kernel(
    const float* __restrict__ rots, const float* __restrict__ fxs,
    const float* __restrict__ cxs, int j,
    float* __restrict__ xarr, float* __restrict__ yarr,
    int* __restrict__ idxarr, float* __restrict__ cnt)
{
  int s = blockIdx.x * 256 + threadIdx.x;      // 0..51199, s = h*400 + w
  int h = s / 400;
  int w = s - h * 400;
  float fx = fxs[j], cx = cxs[j];
  const float* R = rots + j * 9;
  float cr = R[3];        // rots[1][0]
  float sr = -R[0];       // -rots[0][0]
  float t = (2.0f * (float)w + 1.0f - cx) / fx;      // tan(ang)
  float inv = 1.0f / sqrtf(1.0f + t * t);            // cos(ang)
  float ca = (cr + sr * t) * inv;                    // cr*cos + sr*sin
  float sa = (cr * t - sr) * inv;                    // -sr*cos + cr*sin
  float rad = ((float)h * (1.0f / 127.0f)) * 90.50966799187808f;
  float x = 64.0f + rad * ca;
  float y = 64.0f - rad * sa;
  xarr[s] = x;
  yarr[s] = y;
  int xi = (int)fminf(fmaxf(rintf(x), 0.0f), 127.0f);
  int yi = (int)fminf(fmaxf(rintf(y), 0.0f), 127.0f);
  int pix = yi * 128 + xi;
  idxarr[s] = pix;
  atomicAdd(&cnt[pix], 1.0f);
}

// ===================== prefix scan over pixel counts =====================
__global__ __launch_bounds__(256) void prefix_kernel(
    const float* __restrict__ cnt, int* __restrict__ offsets)
{
  __shared__ int sh[256];
  int t = threadIdx.x;
  int base = t * 64;
  int sum = 0;
  for (int i = 0; i < 64; ++i) sum += (int)cnt[base + i];
  sh[t] = sum;
  __syncthreads();
  for (int d = 1; d < 256; d <<= 1) {
    int v = (t >= d) ? sh[t - d] : 0;
    __syncthreads();
    sh[t] += v;
    __syncthreads();
  }
  int run = sh[t] - sum;   // exclusive prefix for this thread's chunk
  for (int i = 0; i < 64; ++i) {
    offsets[base + i] = run;
    run += (int)cnt[base + i];
  }
}

// ===================== fill sorted sample lists =====================
__global__ __launch_bounds__(256) void fill_kernel(
    const int* __restrict__ idxarr, const int* __restrict__ offsets,
    int* __restrict__ cursor, int* __restrict__ order, int* __restrict__ pixs)
{
  int s = blockIdx.x * 256 + threadIdx.x;
  int pix = idxarr[s];
  int pos = offsets[pix] + atomicAdd(&cursor[pix], 1);
  // store the attention-output row index m = w*128 + h  (s = h*400 + w)
  order[pos] = (s % 400) * 128 + (s / 400);
  pixs[pos] = pix;
}

// ===================== transpose: fp32 [256][16384] -> bf16 [16384][256] ===
__global__ __launch_bounds__(256) void transpose_kernel(
    const float* __restrict__ src, ushort* __restrict__ dst)
{
  __shared__ float tile[64][65];   // [p_local][c_local]
  int p0 = blockIdx.x * 64;
  int c0 = blockIdx.y * 64;
  int t = threadIdx.x;
  int pr = (t & 15) * 4;           // p offset
  int cr = t >> 4;                 // c row 0..15
#pragma unroll
  for (int q = 0; q < 4; ++q) {
    int c = cr + q * 16;
    float4 v = *(const float4*)(src + (size_t)(c0 + c) * PIX + p0 + pr);
    tile[pr + 0][c] = v.x;
    tile[pr + 1][c] = v.y;
    tile[pr + 2][c] = v.z;
    tile[pr + 3][c] = v.w;
  }
  __syncthreads();
  int p = t >> 2;
  int ch = (t & 3) * 16;
  ushort tmp[16];
#pragma unroll
  for (int i = 0; i < 16; ++i) tmp[i] = f2b(tile[p][ch + i]);
  ushort* d = dst + (size_t)(p0 + p) * 256 + c0 + ch;
  *(uint4*)(d) = *(uint4*)tmp;
  *(uint4*)(d + 8) = *(uint4*)(tmp + 8);
}

// ===================== bilinear sampler v2: wave=sample, lanes=channels ====
// aT[p][256] bf16 -> a_rects[s][256] bf16. Coalesced corner-row reads.
__global__ __launch_bounds__(256) void sample2_kernel(
    const ushort* __restrict__ aT, const float* __restrict__ xarr,
    const float* __restrict__ yarr, ushort* __restrict__ a_rects)
{
  int s = blockIdx.x * 4 + (threadIdx.x >> 6);
  int c0 = (threadIdx.x & 63) * 4;
  float x = fminf(fmaxf(xarr[s], 0.0f), 127.0f);
  float y = fminf(fmaxf(yarr[s], 0.0f), 127.0f);
  float x0f = floorf(x), y0f = floorf(y);
  int x0 = (int)x0f, y0 = (int)y0f;
  int x1 = min(x0 + 1, 127), y1 = min(y0 + 1, 127);
  float wx = x - x0f, wy = y - y0f;
  float w00 = (1.0f - wx) * (1.0f - wy);
  float w01 = wx * (1.0f - wy);
  float w10 = (1.0f - wx) * wy;
  float w11 = wx * wy;
  ushort4 v00 = *(const ushort4*)(aT + (size_t)(y0 * 128 + x0) * 256 + c0);
  ushort4 v01 = *(const ushort4*)(aT + (size_t)(y0 * 128 + x1) * 256 + c0);
  ushort4 v10 = *(const ushort4*)(aT + (size_t)(y1 * 128 + x0) * 256 + c0);
  ushort4 v11 = *(const ushort4*)(aT + (size_t)(y1 * 128 + x1) * 256 + c0);
  ushort4 o;
  o.x = f2b(w00 * b2f(v00.x) + w01 * b2f(v01.x) + w10 * b2f(v10.x) + w11 * b2f(v11.x));
  o.y = f2b(w00 * b2f(v00.y) + w01 * b2f(v01.y) + w10 * b2f(v10.y) + w11 * b2f(v11.y));
  o.z = f2b(w00 * b2f(v00.z) + w01 * b2f(v01.z) + w10 * b2f(v10.z) + w11 * b2f(v11.z));
  o.w = f2b(w00 * b2f(v00.w) + w01 * b2f(v01.w) + w10 * b2f(v10.w) + w11 * b2f(v11.w));
  *(ushort4*)(a_rects + (size_t)s * 256 + c0) = o;
}

// ===================== f32 -> bf16 bulk convert (float4-wide) ==============
__global__ __launch_bounds__(256) void f2b_kernel(
    const float* __restrict__ in, ushort* __restrict__ out)
{
  int t = blockIdx.x * 256 + threadIdx.x;
  float4 v = ((const float4*)in)[t];
  ushort4 o;
  o.x = f2b(v.x); o.y = f2b(v.y); o.z = f2b(v.z); o.w = f2b(v.w);
  ((ushort4*)out)[t] = o;
}

// ===================== MFMA proj (row-major feat, no LDS) ==================
// feat[s][k] bf16, Wh[f][k] bf16, bias[h][256] f32 ->
// Couth[(w*128+h)*256 + f] bf16   (s = h*400 + w)
__global__ __launch_bounds__(256) void mfma_projS_kernel(
    const ushort* __restrict__ feat, const ushort* __restrict__ Wh,
    const float* __restrict__ bias, ushort* __restrict__ Couth)
{
  int s0 = blockIdx.x * 64;
  int lane = threadIdx.x & 63;
  int wave = threadIdx.x >> 6;
  int col = lane & 15, quad = lane >> 4;
  int fw = wave * 64;
  floatx4 acc[4][4];   // [ts(s)][tf(f)]
#pragma unroll
  for (int i = 0; i < 4; ++i)
#pragma unroll
    for (int jx = 0; jx < 4; ++jx) acc[i][jx] = (floatx4){0.f, 0.f, 0.f, 0.f};

  for (int kb = 0; kb < 256; kb += 32) {
    short8 aop[4], bop[4];
#pragma unroll
    for (int tf = 0; tf < 4; ++tf)
      aop[tf] = *(const short8*)(Wh + (size_t)(fw + tf * 16 + col) * 256 + kb + quad * 8);
#pragma unroll
    for (int ts = 0; ts < 4; ++ts)
      bop[ts] = *(const short8*)(feat + (size_t)(s0 + ts * 16 + col) * 256 + kb + quad * 8);
#pragma unroll
    for (int ts = 0; ts < 4; ++ts)
#pragma unroll
      for (int tf = 0; tf < 4; ++tf)
        acc[ts][tf] = __builtin_amdgcn_mfma_f32_16x16x32_bf16(
            aop[tf], bop[ts], acc[ts][tf], 0, 0, 0);
  }
  // D: col -> s, row=quad*4+r -> f
#pragma unroll
  for (int ts = 0; ts < 4; ++ts) {
    int s = s0 + ts * 16 + col;
    int h = s / 400;
    int w = s - h * 400;
    size_t obase = (size_t)(w * 128 + h) * 256;
#pragma unroll
    for (int tf = 0; tf < 4; ++tf) {
      int f = fw + tf * 16 + quad * 4;
      float4 bv = *(const float4*)(bias + h * 256 + f);
      ushort4 ov;
      ov.x = f2b(acc[ts][tf][0] + bv.x);
      ov.y = f2b(acc[ts][tf][1] + bv.y);
      ov.z = f2b(acc[ts][tf][2] + bv.z);
      ov.w = f2b(acc[ts][tf][3] + bv.w);
      *(ushort4*)(Couth + obase + f) = ov;
    }
  }
}

// ===================== MFMA GEMM: C = A^T(K-major bf16) @ W^T(bf16) ========
// (kept for K/V projections; b features are K-major [k][m])
#define BKP 144   // LDS A row stride in halfs
#define WKP 40    // LDS W row stride in halfs
__global__ __launch_bounds__(256) void mfma_gemmT_kernel(
    const ushort* __restrict__ Ah, int Astride,
    const ushort* __restrict__ Wh, const float* __restrict__ bias,
    ushort* __restrict__ Couth, int Hdim)
{
  __shared__ ushort lA[32 * BKP];
  __shared__ ushort lW[128 * WKP];
  int m0 = blockIdx.x * 128;
  int n0 = blockIdx.y * 128;
  int tid = threadIdx.x;
  int lane = tid & 63;
  int wave = tid >> 6;
  int col = lane & 15;
  int quad = lane >> 4;
  int sw = (wave & 1) * 64;
  int fw = (wave >> 1) * 64;
  floatx4 acc[4][4];
#pragma unroll
  for (int i = 0; i < 4; ++i)
#pragma unroll
    for (int jx = 0; jx < 4; ++jx) acc[i][jx] = (floatx4){0.f, 0.f, 0.f, 0.f};

  for (int kb = 0; kb < 256; kb += 32) {
#pragma unroll
    for (int half = 0; half < 2; ++half) {
      int L = tid + half * 256;
      int r = L >> 4;
      int c = L & 15;
      uint4 v = *(const uint4*)(Ah + (size_t)(kb + r) * Astride + m0 + c * 8);
      int mp = (c * 8) ^ ((r >> 3) * 16);
      *(uint4*)&lA[r * BKP + mp] = v;
    }
#pragma unroll
    for (int half = 0; half < 2; ++half) {
      int L = tid + half * 256;
      int f = L >> 2;
      int seg = L & 3;
      uint4 v = *(const uint4*)(Wh + (size_t)(n0 + f) * 256 + kb + seg * 8);
      *(uint4*)&lW[f * WKP + seg * 8] = v;
    }
    __syncthreads();
    short8 aop[4];
#pragma unroll
    for (int tf = 0; tf < 4; ++tf) {
      int fr = fw + tf * 16 + col;
      aop[tf] = *(const short8*)&lW[fr * WKP + quad * 8];
    }
#pragma unroll
    for (int ts = 0; ts < 4; ++ts) {
      int mi = sw + ts * 16 + col;
      int mp = mi ^ (quad * 16);
      short8 bop;
#pragma unroll
      for (int jx = 0; jx < 8; ++jx)
        bop[jx] = (short)lA[(quad * 8 + jx) * BKP + mp];
#pragma unroll
      for (int tf = 0; tf < 4; ++tf)
        acc[ts][tf] = __builtin_amdgcn_mfma_f32_16x16x32_bf16(
            aop[tf], bop, acc[ts][tf], 0, 0, 0);
    }
    __syncthreads();
  }
#pragma unroll
  for (int ts = 0; ts < 4; ++ts) {
    int m = m0 + sw + ts * 16 + col;
    int h = m / 400;
    int w = m - h * 400;
    size_t obase = (size_t)(w * Hdim + h) * 256;
#pragma unroll
    for (int tf = 0; tf < 4; ++tf) {
      int f = n0 + fw + tf * 16 + quad * 4;
      float4 bv = *(const float4*)(bias + h * 256 + f);
      ushort4 ov;
      ov.x = f2b(acc[ts][tf][0] + bv.x);
      ov.y = f2b(acc[ts][tf][1] + bv.y);
      ov.z = f2b(acc[ts][tf][2] + bv.z);
      ov.w = f2b(acc[ts][tf][3] + bv.w);
      *(ushort4*)(Couth + obase + f) = ov;
    }
  }
}

// ===================== MFMA flash attention =====================
#define KP 40
#define VP 72
#define PP 72
__global__ __launch_bounds__(256) void attn_mfma_kernel(
    const ushort* __restrict__ qh, const ushort* __restrict__ kh,
    const ushort* __restrict__ vh, ushort* __restrict__ obuf)
{
  __shared__ ushort lK[4][64 * KP];
  __shared__ ushort lV[4][32 * VP];
  __shared__ ushort lP[4][16 * PP];
  int b = blockIdx.x;
  int wave = threadIdx.x >> 6;
  int lane = threadIdx.x & 63;
  int head = blockIdx.y * 4 + wave;
  int col = lane & 15, quad = lane >> 4;
  ushort* Kw = lK[wave];
  ushort* Vw = lV[wave];
  ushort* Pw = lP[wave];

  {
    const ushort* ksrc = kh + ((size_t)(b * 64 + lane)) * 256 + head * 32;
    uint4 k0 = *(const uint4*)(ksrc);
    uint4 k1 = *(const uint4*)(ksrc + 8);
    uint4 k2 = *(const uint4*)(ksrc + 16);
    uint4 k3 = *(const uint4*)(ksrc + 24);
    ushort* kd = Kw + lane * KP;
    *(uint4*)(kd) = k0; *(uint4*)(kd + 8) = k1;
    *(uint4*)(kd + 16) = k2; *(uint4*)(kd + 24) = k3;
    const ushort* vsrc = vh + ((size_t)(b * 64 + lane)) * 256 + head * 32;
    ushort vr[32];
    *(uint4*)(vr) = *(const uint4*)(vsrc);
    *(uint4*)(vr + 8) = *(const uint4*)(vsrc + 8);
    *(uint4*)(vr + 16) = *(const uint4*)(vsrc + 16);
    *(uint4*)(vr + 24) = *(const uint4*)(vsrc + 24);
#pragma unroll
    for (int d = 0; d < 32; ++d) Vw[d * VP + lane] = vr[d];
  }
  __syncthreads();

  const float scl = 0.17677669529663687f;   // 1/sqrt(32)
  for (int qt = 0; qt < 8; ++qt) {
    short8 aq = *(const short8*)(qh +
        ((size_t)(b * 128 + qt * 16 + col)) * 256 + head * 32 + quad * 8);
    floatx4 s0 = {0.f,0.f,0.f,0.f}, s1 = s0, s2 = s0, s3 = s0;
    {
      short8 b0 = *(const short8*)(Kw + (0 * 16 + col) * KP + quad * 8);
      short8 b1 = *(const short8*)(Kw + (1 * 16 + col) * KP + quad * 8);
      short8 b2 = *(const short8*)(Kw + (2 * 16 + col) * KP + quad * 8);
      short8 b3 = *(const short8*)(Kw + (3 * 16 + col) * KP + quad * 8);
      s0 = __builtin_amdgcn_mfma_f32_16x16x32_bf16(aq, b0, s0, 0, 0, 0);
      s1 = __builtin_amdgcn_mfma_f32_16x16x32_bf16(aq, b1, s1, 0, 0, 0);
      s2 = __builtin_amdgcn_mfma_f32_16x16x32_bf16(aq, b2, s2, 0, 0, 0);
      s3 = __builtin_amdgcn_mfma_f32_16x16x32_bf16(aq, b3, s3, 0, 0, 0);
    }
    float e[4][4], mr[4], sm[4];
#pragma unroll
    for (int r = 0; r < 4; ++r) {
      float v0 = s0[r] * scl, v1 = s1[r] * scl;
      float v2 = s2[r] * scl, v3 = s3[r] * scl;
      e[0][r] = v0; e[1][r] = v1; e[2][r] = v2; e[3][r] = v3;
      mr[r] = fmaxf(fmaxf(v0, v1), fmaxf(v2, v3));
    }
#pragma unroll
    for (int mask = 1; mask <= 8; mask <<= 1)
#pragma unroll
      for (int r = 0; r < 4; ++r)
        mr[r] = fmaxf(mr[r], __shfl_xor(mr[r], mask, 64));
#pragma unroll
    for (int r = 0; r < 4; ++r) {
      float acc = 0.f;
#pragma unroll
      for (int t = 0; t < 4; ++t) {
        float ev = __expf(e[t][r] - mr[r]);
        e[t][r] = ev;
        acc += ev;
      }
      sm[r] = acc;
    }
#pragma unroll
    for (int mask = 1; mask <= 8; mask <<= 1)
#pragma unroll
      for (int r = 0; r < 4; ++r)
        sm[r] += __shfl_xor(sm[r], mask, 64);
#pragma unroll
    for (int t = 0; t < 4; ++t)
#pragma unroll
      for (int r = 0; r < 4; ++r)
        Pw[(quad * 4 + r) * PP + t * 16 + col] = f2b(e[t][r]);
    __syncthreads();
    floatx4 o0 = {0.f,0.f,0.f,0.f}, o1 = o0;
#pragma unroll
    for (int c = 0; c < 2; ++c) {
      short8 ap = *(const short8*)(Pw + col * PP + c * 32 + quad * 8);
      short8 v0 = *(const short8*)(Vw + col * VP + c * 32 + quad * 8);
      short8 v1 = *(const short8*)(Vw + (16 + col) * VP + c * 32 + quad * 8);
      o0 = __builtin_amdgcn_mfma_f32_16x16x32_bf16(ap, v0, o0, 0, 0, 0);
      o1 = __builtin_amdgcn_mfma_f32_16x16x32_bf16(ap, v1, o1, 0, 0, 0);
    }
#pragma unroll
    for (int r = 0; r < 4; ++r) {
      float iv = 1.0f / sm[r];
      size_t row = (size_t)(b * 128 + qt * 16 + quad * 4 + r) * 256 + head * 32;
      obuf[row + col] = f2b(o0[r] * iv);
      obuf[row + 16 + col] = f2b(o1[r] * iv);
    }
    __syncthreads();
  }
}

// ===================== GEMM (A M-major fp32): C = A * W^T + biasf ==========
__global__ __launch_bounds__(256) void gemmN_kernel(
    const float* __restrict__ A, const float* __restrict__ Wt,
    const float* __restrict__ biasf, float* __restrict__ Cout, int mode)
{
  __shared__ float As[64][17];
  __shared__ float Ws[16][65];
  int m0 = blockIdx.x * 64;
  int n0 = blockIdx.y * 64;
  int tid = threadIdx.x;
  int tx = tid & 15, ty = tid >> 4;
  float acc[4][4] = {};
  for (int k0 = 0; k0 < 256; k0 += 16) {
    {
      int m = tid >> 2;
      int kq = (tid & 3) << 2;
      float4 v = *(const float4*)(A + (size_t)(m0 + m) * 256 + k0 + kq);
      As[m][kq + 0] = v.x; As[m][kq + 1] = v.y;
      As[m][kq + 2] = v.z; As[m][kq + 3] = v.w;
    }
    {
      int f = tid >> 2;
      int kq = (tid & 3) << 2;
      float4 v = *(const float4*)(Wt + (size_t)(n0 + f) * 256 + k0 + kq);
      Ws[kq + 0][f] = v.x; Ws[kq + 1][f] = v.y;
      Ws[kq + 2][f] = v.z; Ws[kq + 3][f] = v.w;
    }
    __syncthreads();
#pragma unroll
    for (int kk = 0; kk < 16; ++kk) {
      float a[4], b[4];
#pragma unroll
      for (int i = 0; i < 4; ++i) a[i] = As[ty * 4 + i][kk];
#pragma unroll
      for (int jj = 0; jj < 4; ++jj) b[jj] = Ws[kk][tx * 4 + jj];
#pragma unroll
      for (int i = 0; i < 4; ++i)
#pragma unroll
        for (int jj = 0; jj < 4; ++jj) acc[i][jj] += a[i] * b[jj];
    }
    __syncthreads();
  }
#pragma unroll
  for (int i = 0; i < 4; ++i) {
    int m = m0 + ty * 4 + i;
    int f = n0 + tx * 4;
    float4 ov;
    if (mode == 0) {
      float4 bv = *(const float4*)(biasf + f);
      ov.x = acc[i][0] + bv.x; ov.y = acc[i][1] + bv.y;
      ov.z = acc[i][2] + bv.z; ov.w = acc[i][3] + bv.w;
    } else {
      ov.x = acc[i][0]; ov.y = acc[i][1];
      ov.z = acc[i][2]; ov.w = acc[i][3];
    }
    *(float4*)(Cout + (size_t)m * 256 + f) = ov;
  }
}

// ===================== GEMM A[m][k] * B[k][n] (effective weights) ==========
__global__ __launch_bounds__(256) void gemm_ab_kernel(
    const float* __restrict__ in_w, const float* __restrict__ Wq,
    const float* __restrict__ Wk, const float* __restrict__ Wv,
    float* __restrict__ weff)
{
  int z = blockIdx.z;
  const float* A = in_w + (size_t)z * 65536;
  const float* B = (z == 0) ? Wq : ((z == 1) ? Wk : Wv);
  float* C = weff + (size_t)z * 65536;
  __shared__ float As[64][17];
  __shared__ float Bs[16][64];
  int m0 = blockIdx.x * 64;
  int n0 = blockIdx.y * 64;
  int tid = threadIdx.x;
  int tx = tid & 15, ty = tid >> 4;
  float acc[4][4] = {};
  for (int k0 = 0; k0 < 256; k0 += 16) {
    {
      int m = tid >> 2;
      int kq = (tid & 3) << 2;
      float4 v = *(const float4*)(A + (size_t)(m0 + m) * 256 + k0 + kq);
      As[m][kq + 0] = v.x; As[m][kq + 1] = v.y;
      As[m][kq + 2] = v.z; As[m][kq + 3] = v.w;
    }
    {
      int k = tid >> 4;
      int nq = (tid & 15) << 2;
      float4 v = *(const float4*)(B + (size_t)(k0 + k) * 256 + n0 + nq);
      *(float4*)(&Bs[k][nq]) = v;
    }
    __syncthreads();
#pragma unroll
    for (int kk = 0; kk < 16; ++kk) {
      float a[4], b[4];
#pragma unroll
      for (int i = 0; i < 4; ++i) a[i] = As[ty * 4 + i][kk];
#pragma unroll
      for (int jj = 0; jj < 4; ++jj) b[jj] = Bs[kk][tx * 4 + jj];
#pragma unroll
      for (int i = 0; i < 4; ++i)
#pragma unroll
        for (int jj = 0; jj < 4; ++jj) acc[i][jj] += a[i] * b[jj];
    }
    __syncthreads();
  }
#pragma unroll
  for (int i = 0; i < 4; ++i) {
    int m = m0 + ty * 4 + i;
    *(float4*)(C + (size_t)m * 256 + n0 + tx * 4) = *(float4*)&acc[i][0];
  }
}

// ===================== effective biases =====================
__global__ void beff_kernel(const float* __restrict__ in_w, const float* __restrict__ in_b,
                            const float* __restrict__ bq, const float* __restrict__ bk,
                            const float* __restrict__ bv, float* __restrict__ beff)
{
  int z = blockIdx.x;
  int f = threadIdx.x;
  const float* bsrc = (z == 0) ? bq : ((z == 1) ? bk : bv);
  const float* row = in_w + (size_t)(z * 256 + f) * 256;
  float acc = in_b[z * 256 + f];
  for (int e = 0; e < 256; ++e) acc += row[e] * bsrc[e];
  beff[z * 256 + f] = acc;
}

// ===================== segmented reduction over sorted samples =============
#define CH 64
__global__ __launch_bounds__(256) void segred_kernel(
    const ushort* __restrict__ obuf, const int* __restrict__ order,
    const int* __restrict__ pixs, float* __restrict__ osum)
{
  __shared__ int lm[CH];
  __shared__ int lp[CH + 2];
  int s0 = blockIdx.x * CH;
  int t = threadIdx.x;
  if (t < CH) {
    lm[t] = order[s0 + t];
    lp[t + 1] = pixs[s0 + t];
  } else if (t == CH) {
    lp[0] = (s0 > 0) ? pixs[s0 - 1] : -1;
  } else if (t == CH + 1) {
    lp[CH + 1] = (s0 + CH < MS) ? pixs[s0 + CH] : -2;
  }
  __syncthreads();
  int c = t;
  float va[8];
#pragma unroll
  for (int k = 0; k < 8; ++k)
    va[k] = b2f(obuf[(size_t)lm[k] * 256 + c]);
  float acc = 0.0f;
  int runBegin = 0;
#pragma unroll
  for (int i = 0; i < CH; ++i) {
    float v = va[i & 7];
    if (i + 8 < CH) va[i & 7] = b2f(obuf[(size_t)lm[i + 8] * 256 + c]);
    acc += v;
    int p = lp[i + 1];
    bool last = (i == CH - 1);
    if (last || p != lp[i + 2]) {
      bool pBeg = (runBegin == 0) && (p == lp[0]);
      bool pEnd = last && (p == lp[CH + 1]);
      float* dst = osum + (size_t)p * 256 + c;
      if (pBeg || pEnd) atomicAdd(dst, acc);
      else *dst = acc;
      acc = 0.0f;
      runBegin = i + 1;
    }
  }
}

// ===================== MFMA out-proj: enhT = out_w @ osum^T ================
__global__ __launch_bounds__(256) void mfma_outproj_kernel(
    const float* __restrict__ osum, const ushort* __restrict__ out_wh,
    float* __restrict__ enhT)
{
  int p0 = blockIdx.x * 64;
  int lane = threadIdx.x & 63;
  int wave = threadIdx.x >> 6;
  int col = lane & 15, quad = lane >> 4;
  int fw = wave * 64;
  floatx4 acc[4][4];
#pragma unroll
  for (int i = 0; i < 4; ++i)
#pragma unroll
    for (int jx = 0; jx < 4; ++jx) acc[i][jx] = (floatx4){0.f, 0.f, 0.f, 0.f};

  for (int kb = 0; kb < 256; kb += 32) {
    short8 aop[4], bop[4];
#pragma unroll
    for (int tf = 0; tf < 4; ++tf)
      aop[tf] = *(const short8*)(out_wh +
          (size_t)(fw + tf * 16 + col) * 256 + kb + quad * 8);
#pragma unroll
    for (int ts = 0; ts < 4; ++ts) {
      const float* brow = osum + (size_t)(p0 + ts * 16 + col) * 256 + kb + quad * 8;
      float4 f0 = *(const float4*)brow;
      float4 f1 = *(const float4*)(brow + 4);
      short8 bv;
      bv[0] = (short)f2b(f0.x); bv[1] = (short)f2b(f0.y);
      bv[2] = (short)f2b(f0.z); bv[3] = (short)f2b(f0.w);
      bv[4] = (short)f2b(f1.x); bv[5] = (short)f2b(f1.y);
      bv[6] = (short)f2b(f1.z); bv[7] = (short)f2b(f1.w);
      bop[ts] = bv;
    }
#pragma unroll
    for (int ts = 0; ts < 4; ++ts)
#pragma unroll
      for (int tf = 0; tf < 4; ++tf)
        acc[ts][tf] = __builtin_amdgcn_mfma_f32_16x16x32_bf16(
            aop[tf], bop[ts], acc[ts][tf], 0, 0, 0);
  }
#pragma unroll
  for (int ts = 0; ts < 4; ++ts) {
    int p = p0 + ts * 16 + col;
#pragma unroll
    for (int tf = 0; tf < 4; ++tf) {
      int f = fw + tf * 16 + quad * 4;
#pragma unroll
      for (int r = 0; r < 4; ++r)
        enhT[(size_t)(f + r) * PIX + p] = acc[ts][tf][r];
    }
  }
}

// ===================== residual update / final (elementwise, [c][p]) =======
__global__ __launch_bounds__(256) void update_kernel(
    const float* __restrict__ asrc, float* __restrict__ adst,
    const float* __restrict__ enhT, const float* __restrict__ cnt,
    const float* __restrict__ out_b, float scale)
{
  int t = blockIdx.x * 256 + threadIdx.x;
  int base = t * 4;
  int c = base >> 14;
  int p = base & (PIX - 1);
  float ob = out_b[c];
  float4 e = ((const float4*)enhT)[t];
  float4 cn = *(const float4*)(cnt + p);
  float4 a = ((const float4*)asrc)[t];
  float4 o;
  o.x = a.x + scale * (e.x + cn.x * ob) / fmaxf(cn.x, 1.0f);
  o.y = a.y + scale * (e.y + cn.y * ob) / fmaxf(cn.y, 1.0f);
  o.z = a.z + scale * (e.z + cn.z * ob) / fmaxf(cn.z, 1.0f);
  o.w = a.w + scale * (e.w + cn.w * ob) / fmaxf(cn.w, 1.0f);
  ((float4*)adst)[t] = o;
}

// ===================== launch =====================
extern "C" void kernel_launch(void* const* d_in, const int* in_sizes, int n_in,
                              void* d_out, int out_size, void* d_ws, size_t ws_size,
                              hipStream_t stream) {
  const float* list_a = (const float*)d_in[0];
  const float* list_b = (const float*)d_in[1];
  const float* rots   = (const float*)d_in[3];
  const float* fxs    = (const float*)d_in[5];
  const float* cxs    = (const float*)d_in[6];
  const float* pos_a  = (const float*)d_in[7];
  const float* pos_b  = (const float*)d_in[8];
  const float* Wq     = (const float*)d_in[9];
  const float* bq     = (const float*)d_in[10];
  const float* Wk     = (const float*)d_in[11];
  const float* bk     = (const float*)d_in[12];
  const float* Wv     = (const float*)d_in[13];
  const float* bv     = (const float*)d_in[14];
  const float* in_w   = (const float*)d_in[15];
  const float* in_b   = (const float*)d_in[16];
  const float* out_w  = (const float*)d_in[17];
  const float* out_b  = (const float*)d_in[18];

  float* ws      = (float*)d_ws;
  float* weff    = ws;                          // 196608 f
  float* beff    = weff + 196608;               // 768 f
  float* qpos    = beff + 768;                  // 32768 f
  float* kpos    = qpos + 32768;                // 16384 f
  float* vpos    = kpos + 16384;                // 16384 f
  float* a_cur   = vpos + 16384;                // 4194304 f
  float* xarr    = a_cur + 4194304;             // 51200 f
  float* yarr    = xarr + 51200;                // 51200 f
  int*   idxarr  = (int*)(yarr + 51200);        // 51200
  float* cnt     = (float*)(idxarr + 51200);    // 16384 f
  int*   cursor  = (int*)(cnt + 16384);         // 16384
  int*   offs    = cursor + 16384;              // 16384
  int*   order   = offs + 16384;                // 51200
  int*   pixs    = order + 51200;               // 51200
  float* osum    = (float*)(pixs + 51200);      // 4194304 f
  ushort* weffh  = (ushort*)(osum + 4194304);   // 196608 h
  ushort* out_wh = weffh + 196608;              // 65536 h
  ushort* a_rects = out_wh + 65536;             // 13107200 h (obuf alias)
  ushort* bh     = a_rects + 13107200;          // 6553600 h
  ushort* qh     = bh + 6553600;                // 13107200 h
  ushort* kh     = qh + 13107200;               // 6553600 h (enhT alias ->)
  ushort* vh     = kh + 6553600;                // 6553600 h
  ushort* aT     = vh + 6553600;                // 4194304 h
  ushort* obufh  = a_rects;                     // alias: a_rects dead after Q-proj
  float* enhT    = (float*)kh;                  // alias: kh+vh dead after attn

  // effective weights + biases (tiny)
  gemm_ab_kernel<<<dim3(4, 4, 3), 256, 0, stream>>>(in_w, Wq, Wk, Wv, weff);
  beff_kernel<<<3, 256, 0, stream>>>(in_w, in_b, bq, bk, bv, beff);
  f2b_kernel<<<192, 256, 0, stream>>>(weff, weffh);
  f2b_kernel<<<64, 256, 0, stream>>>(out_w, out_wh);

  // positional bias tables: pos @ Weff^T + beff
  gemmN_kernel<<<dim3(2, 4), 256, 0, stream>>>(pos_a, weff, beff, qpos, 0);
  gemmN_kernel<<<dim3(1, 4), 256, 0, stream>>>(pos_b, weff + 65536, beff + 256, kpos, 0);
  gemmN_kernel<<<dim3(1, 4), 256, 0, stream>>>(pos_b, weff + 131072, beff + 512, vpos, 0);

  for (int jj = 0; jj < 2; ++jj) {
    int j = jj ? 3 : 0;
    const float* asrc = jj ? a_cur : list_a;
    hipMemsetAsync(cnt, 0, (size_t)2 * 16384 * sizeof(float), stream);  // cnt + cursor
    hipMemsetAsync(osum, 0, (size_t)4194304 * sizeof(float), stream);
    coords_kernel<<<200, 256, 0, stream>>>(rots, fxs, cxs, j, xarr, yarr, idxarr, cnt);
    prefix_kernel<<<1, 256, 0, stream>>>(cnt, offs);
    fill_kernel<<<200, 256, 0, stream>>>(idxarr, offs, cursor, order, pixs);
    // image -> pixel-major bf16, then wave-per-sample bilinear
    transpose_kernel<<<dim3(256, 4), 256, 0, stream>>>(asrc, aT);
    sample2_kernel<<<12800, 256, 0, stream>>>(aT, xarr, yarr, a_rects);
    const float* bsrc = list_b + (size_t)j * 6553600;
    f2b_kernel<<<6400, 256, 0, stream>>>(bsrc, bh);
    // Q projection: direct row-major MFMA (no LDS)
    mfma_projS_kernel<<<800, 256, 0, stream>>>(a_rects, weffh, qpos, qh);
    // K/V projections from K-major b
    mfma_gemmT_kernel<<<dim3(200, 2), 256, 0, stream>>>(bh, MB, weffh + 65536, kpos, kh, 64);
    mfma_gemmT_kernel<<<dim3(200, 2), 256, 0, stream>>>(bh, MB, weffh + 131072, vpos, vh, 64);
    // MFMA flash attention (O bf16 into obufh = a_rects region)
    attn_mfma_kernel<<<dim3(400, 2), 256, 0, stream>>>(qh, kh, vh, obufh);
    // segmented reduction of O over sorted samples -> osum fp32
    segred_kernel<<<800, 256, 0, stream>>>(obufh, order, pixs, osum);
    // MFMA out-proj directly into transposed layout [c][p]
    mfma_outproj_kernel<<<256, 256, 0, stream>>>(osum, out_wh, enhT);
    update_kernel<<<4096, 256, 0, stream>>>(asrc, jj ? (float*)d_out : a_cur,
                                            enhT, cnt, out_b, jj ? 2.0f : 1.0f);
  }
}